// Round 10
// baseline (14674.576 us; speedup 1.0000x reference)
//
#include <hip/hip_runtime.h>
#include <math.h>

// Problem constants
#define N_TOK   16384
#define N_E     16384
#define CDIM    256
#define NCH     8
#define CHSZ    (N_E / NCH)      // 2048 codes per chunk
#define L2E100  144.26950408889634f   // 100 * log2(e)
#define DELTA_C 0.06f            // candidate window below running row max
#define EPS_NT  0.008f           // near-tie window for fp64 argmin re-rank
#define CAP_POOL 2097152u        // global candidate pool entries (mean ~1.2M)
#define NT_CAP  65536u

typedef __attribute__((ext_vector_type(8))) short short8;
typedef __attribute__((ext_vector_type(4))) float f32x4;

// ---- workspace layout (float offsets), total 51.1 MB (proven ws >= 52.5 MB) ----
#define OFF_A2   0u          // ushort[16384*256] bf16-hi normalized z (token-major)
#define OFF_B2   2097152u    // ushort[16384*256] bf16-hi normalized emb
#define OFF_ZT   4194304u    // float[16384*256] RAW z, token-major (for fp64 refine)
#define OFF_RMX  8388608u    // 16384 u32 ordered-key row max
#define OFF_ZR   8404992u    // 16384 Z
#define OFF_ER   8421376u    // 16384 E (logit units)
#define OFF_CS   8437760u    // 16384 colsum
#define OFF_SC   8454144u    // 16 scalars
#define OFF_RK   8454160u    // 16384 u64 rowkey (8B aligned)
#define OFF_NT   8486928u    // 65536 u32 near-tie list
#define OFF_NTC  8552464u    // [0]=near-tie cnt, [1]=pool cnt
#define OFF_IDX  8552480u    // 16384 int
#define OFF_CAND 8568864u    // u64[CAP_POOL] {f32 t | row<<14|col} (8B aligned)
// ends at 12,763,168 floats = 51.05 MB

__device__ __forceinline__ unsigned short f2bf(float x) {
  unsigned u = __float_as_uint(x);
  unsigned r = (u + 0x7fffu + ((u >> 16) & 1u)) >> 16;
  return (unsigned short)r;
}
__device__ __forceinline__ float bf2f(unsigned short h) {
  return __uint_as_float(((unsigned)h) << 16);
}
__device__ __forceinline__ unsigned fkey(float f) {      // order-preserving float->uint
  unsigned u = __float_as_uint(f);
  return (u & 0x80000000u) ? ~u : (u | 0x80000000u);
}
__device__ __forceinline__ float keyf(unsigned k) {
  return (k & 0x80000000u) ? __uint_as_float(k ^ 0x80000000u) : __uint_as_float(~k);
}

__device__ __forceinline__ void async_load16(const void* g, void* l) {
  __builtin_amdgcn_global_load_lds((const __attribute__((address_space(1))) void*)g,
                                   (__attribute__((address_space(3))) void*)l, 16, 0, 0);
}

__device__ __forceinline__ float blockReduceSum256(float v, float* sbuf) {
  __syncthreads();
  v += __shfl_down(v, 32);
  v += __shfl_down(v, 16);
  v += __shfl_down(v, 8);
  v += __shfl_down(v, 4);
  v += __shfl_down(v, 2);
  v += __shfl_down(v, 1);
  const int tid = threadIdx.x;
  if ((tid & 63) == 0) sbuf[tid >> 6] = v;
  __syncthreads();
  return sbuf[0] + sbuf[1] + sbuf[2] + sbuf[3];
}

__global__ __launch_bounds__(256) void k_zero(float* __restrict__ colsum,
                                              float* __restrict__ scalars,
                                              unsigned long long* __restrict__ rowkey,
                                              unsigned* __restrict__ ntc,
                                              unsigned* __restrict__ rowMaxU,
                                              float* __restrict__ Zr,
                                              float* __restrict__ Er) {
  const int i = blockIdx.x * 256 + threadIdx.x;
  colsum[i] = 0.f;
  rowkey[i] = ~0ull;
  rowMaxU[i] = 0u;
  Zr[i] = 0.f;
  Er[i] = 0.f;
  if (i < 16) { scalars[i] = 0.f; ntc[i] = 0u; }
}

// ---------- wave-per-row emb normalize ----------
__global__ __launch_bounds__(256) void k_norm_emb(const float* __restrict__ emb,
                                                  unsigned short* __restrict__ B2) {
  const int tid = threadIdx.x, lane = tid & 63, wv = tid >> 6;
  const int k = blockIdx.x * 4 + wv;
  const float4 v = *(const float4*)&emb[(size_t)k * CDIM + lane * 4];
  float ss = v.x * v.x + v.y * v.y + v.z * v.z + v.w * v.w;
#pragma unroll
  for (int off = 1; off < 64; off <<= 1) ss += __shfl_xor(ss, off);
  const float r = 1.0f / fmaxf(sqrtf(ss), 1e-12f);
  ushort4 o;
  o.x = f2bf(v.x * r); o.y = f2bf(v.y * r);
  o.z = f2bf(v.z * r); o.w = f2bf(v.w * r);
  *(ushort4*)&B2[(size_t)k * CDIM + lane * 4] = o;
}

// ---------- coalesced z normalize + token-major raw copy (zT) ----------
__global__ __launch_bounds__(256) void k_norm_z(const float* __restrict__ z,
                                                unsigned short* __restrict__ A2,
                                                float* __restrict__ zT) {
  __shared__ float ssb[4][64];
  __shared__ float rn[64];
  __shared__ unsigned short tile[64 * 264];
  __shared__ float tileF[64 * 260];
  const int b = blockIdx.x >> 4, hw0 = (blockIdx.x & 15) * 64;
  const int tid = threadIdx.x, cg = tid >> 6, hwl = tid & 63;
  float ss = 0.f;
#pragma unroll 8
  for (int i = 0; i < 64; ++i) {
    const int c = cg + i * 4;
    const float x = z[((size_t)(b * CDIM + c) << 10) + hw0 + hwl];
    ss = fmaf(x, x, ss);
  }
  ssb[cg][hwl] = ss;
  __syncthreads();
  if (tid < 64) {
    const float t = ssb[0][tid] + ssb[1][tid] + ssb[2][tid] + ssb[3][tid];
    rn[tid] = 1.0f / fmaxf(sqrtf(t), 1e-12f);
  }
  __syncthreads();
  const float r = rn[hwl];
#pragma unroll 8
  for (int i = 0; i < 64; ++i) {
    const int c = cg + i * 4;
    const float x = z[((size_t)(b * CDIM + c) << 10) + hw0 + hwl];
    tile[hwl * 264 + c] = f2bf(x * r);
    tileF[hwl * 260 + c] = x;
  }
  __syncthreads();
  const int rr = tid >> 5, tt = tid & 31;
#pragma unroll
  for (int it = 0; it < 8; ++it) {
    const int row = rr + 8 * it;
    const int token = b * 1024 + hw0 + row;
    const uint4 v = *(const uint4*)&tile[row * 264 + tt * 8];
    *(uint4*)&A2[(size_t)token * CDIM + tt * 8] = v;
    const float4 f0 = *(const float4*)&tileF[row * 260 + tt * 4];
    const float4 f1 = *(const float4*)&tileF[row * 260 + 128 + tt * 4];
    *(float4*)&zT[(size_t)token * CDIM + tt * 4] = f0;
    *(float4*)&zT[(size_t)token * CDIM + 128 + tt * 4] = f1;
  }
}

// ============ pass 1: round-8 shape (2 blocks/CU), t = 2*dot, global pool ============
__global__ __launch_bounds__(256, 2) void k_pass1(const unsigned short* __restrict__ A2,
    const unsigned short* __restrict__ B2,
    unsigned long long* __restrict__ cand, unsigned* __restrict__ ntc,
    unsigned* __restrict__ rowMaxU) {
  __shared__ alignas(16) unsigned short Af[64 * 256];     // 32 KB full-K A tile
  __shared__ alignas(16) unsigned short Bt[2][128 * 64];  // 2 x 16 KB B dbuf
  __shared__ unsigned smaxU[64];
  const int chunk = blockIdx.x, rt = blockIdx.y;
  const int r0 = rt * 64, k0 = chunk * CHSZ;
  const int tid = threadIdx.x, lane = tid & 63, w = tid >> 6;
  const int wrr = (w & 1) * 32, wc = (w >> 1) * 64;
  const int l15 = lane & 15, quad = lane >> 4;
  unsigned* candCnt = ntc + 1;

  if (tid < 64) smaxU[tid] = 0u;

  // stage full-K A tile (swizzle: position cg holds global group cg^(row&7))
#pragma unroll
  for (int i = 0; i < 8; ++i) {
    const int lin = i * 256 + tid;
    const int row = lin >> 5, cg = lin & 31;
    const int gcg = cg ^ (row & 7);
    async_load16((const char*)A2 + ((size_t)(r0 + row) * CDIM + gcg * 8) * 2,
                 (char*)Af + lin * 16);
  }
  // per-thread B staging bases
  const unsigned short* bsrc[4];
  unsigned bdst[4];
#pragma unroll
  for (int i = 0; i < 4; ++i) {
    const int lin = i * 256 + tid;
    const int row = lin >> 3, cg = lin & 7;
    const int gcg = cg ^ (row & 7);
    bsrc[i] = B2 + (size_t)(k0 + row) * CDIM + gcg * 8;
    bdst[i] = (unsigned)lin * 16u;
  }
#pragma unroll
  for (int i = 0; i < 4; ++i)
    async_load16(bsrc[i], (char*)Bt[0] + bdst[i]);

  // hoisted LDS read offsets
  int aoff[2][2], boff[4][2];
#pragma unroll
  for (int ti = 0; ti < 2; ++ti) {
    const int ar = wrr + ti * 16 + l15;
#pragma unroll
    for (int kk = 0; kk < 2; ++kk)
      aoff[ti][kk] = ar * 256 + ((((kk << 2) | quad) ^ (ar & 7)) * 8);
  }
#pragma unroll
  for (int tj = 0; tj < 4; ++tj) {
    const int br = wc + tj * 16 + l15;
#pragma unroll
    for (int kk = 0; kk < 2; ++kk)
      boff[tj][kk] = br * 64 + ((((kk << 2) | quad) ^ (br & 7)) * 8);
  }
  __syncthreads();

  f32x4 acc[2][4];

  for (int ct = 0; ct < 16; ++ct) {
#pragma unroll
    for (int ti = 0; ti < 2; ++ti)
#pragma unroll
      for (int tj = 0; tj < 4; ++tj) acc[ti][tj] = (f32x4){0.f, 0.f, 0.f, 0.f};

#pragma unroll
    for (int st = 0; st < 4; ++st) {
      if (!(ct == 15 && st == 3)) {
        const int noff = (st < 3) ? (st + 1) * 64 : 32768;
        char* dbuf = (char*)Bt[(st + 1) & 1];
#pragma unroll
        for (int i = 0; i < 4; ++i)
          async_load16(bsrc[i] + noff, dbuf + bdst[i]);
      }
      const unsigned short* bp = Bt[st & 1];
#pragma unroll
      for (int kk = 0; kk < 2; ++kk) {
        short8 af[2], bfr[4];
#pragma unroll
        for (int ti = 0; ti < 2; ++ti)
          af[ti] = *(const short8*)&Af[aoff[ti][kk] + st * 64];
#pragma unroll
        for (int tj = 0; tj < 4; ++tj)
          bfr[tj] = *(const short8*)&bp[boff[tj][kk]];
#pragma unroll
        for (int ti = 0; ti < 2; ++ti)
#pragma unroll
          for (int tj = 0; tj < 4; ++tj)
            acc[ti][tj] = __builtin_amdgcn_mfma_f32_16x16x32_bf16(af[ti], bfr[tj], acc[ti][tj], 0, 0, 0);
      }
      if (st == 3) {
        const int kb = k0 + ct * 128;
#pragma unroll
        for (int ti = 0; ti < 2; ++ti)
#pragma unroll
          for (int tj = 0; tj < 4; ++tj) {
            f32x4 a = acc[ti][tj];
#pragma unroll
            for (int r = 0; r < 4; ++r) a[r] = a[r] + a[r];   // t = 2*dot
            acc[ti][tj] = a;
          }
#pragma unroll
        for (int ti = 0; ti < 2; ++ti)
#pragma unroll
          for (int r = 0; r < 4; ++r) {
            float mt = fmaxf(fmaxf(acc[ti][0][r], acc[ti][1][r]),
                             fmaxf(acc[ti][2][r], acc[ti][3][r]));
            mt = fmaxf(mt, __shfl_xor(mt, 1));
            mt = fmaxf(mt, __shfl_xor(mt, 2));
            mt = fmaxf(mt, __shfl_xor(mt, 4));
            mt = fmaxf(mt, __shfl_xor(mt, 8));
            if (l15 == 0) atomicMax(&smaxU[wrr + ti * 16 + quad * 4 + r], fkey(mt));
          }
        __syncthreads();
#pragma unroll
        for (int ti = 0; ti < 2; ++ti)
#pragma unroll
          for (int r = 0; r < 4; ++r) {
            const int rowloc = wrr + ti * 16 + quad * 4 + r;
            const float thr = keyf(smaxU[rowloc]) - DELTA_C;
            const unsigned rowg = (unsigned)(r0 + rowloc);
#pragma unroll
            for (int tj = 0; tj < 4; ++tj) {
              const float t = acc[ti][tj][r];
              if (t >= thr) {
                const unsigned slot = atomicAdd(candCnt, 1u);
                if (slot < CAP_POOL) {
                  const unsigned pr = (rowg << 14) | (unsigned)(kb + wc + tj * 16 + l15);
                  cand[slot] = ((unsigned long long)__float_as_uint(t) << 32) | pr;
                }
              }
            }
          }
      }
      __syncthreads();
    }
#pragma unroll
    for (int i = 0; i < 4; ++i) bsrc[i] += 32768;
  }
  if (tid < 64) atomicMax(&rowMaxU[r0 + tid], smaxU[tid]);
}

// ---------- pool sweep: Z, E, near-tie list ----------
__global__ __launch_bounds__(256) void k_cstat(const unsigned long long* __restrict__ cand,
    const unsigned* __restrict__ ntc_in, const unsigned* __restrict__ rowMaxU,
    float* __restrict__ Zr, float* __restrict__ Er,
    unsigned* __restrict__ ntList, unsigned* __restrict__ ntc) {
  const unsigned total = ntc_in[1] < CAP_POOL ? ntc_in[1] : CAP_POOL;
  const unsigned stride = gridDim.x * 256;
  const int tid = threadIdx.x, lane = tid & 63;
  const unsigned lim = (total + stride - 1u) / stride * stride;
  for (unsigned i = blockIdx.x * 256 + tid; i < lim; i += stride) {
    bool nt = false;
    unsigned pr = 0u;
    if (i < total) {
      const unsigned long long e = cand[i];
      pr = (unsigned)(e & 0xFFFFFFFu);
      const float t = __uint_as_float((unsigned)(e >> 32));
      const int n = (int)(pr >> 14);
      const float d = t - keyf(rowMaxU[n]);
      const float ex = exp2f(d * L2E100);
      atomicAdd(&Zr[n], ex);
      atomicAdd(&Er[n], d * 100.0f * ex);
      nt = (d >= -EPS_NT);
    }
    const unsigned long long mask = __ballot(nt);
    const unsigned cw = (unsigned)__popcll(mask);
    unsigned base = 0u;
    if (lane == 0 && cw) base = atomicAdd(ntc, cw);
    base = __shfl((int)base, 0);
    if (nt) {
      const unsigned off = (unsigned)__popcll(mask & ((1ull << lane) - 1ull));
      const unsigned s = base + off;
      if (s < NT_CAP) ntList[s] = pr;
    }
  }
}

// ---------- pool sweep: colsum ----------
__global__ __launch_bounds__(256) void k_ccol(const unsigned long long* __restrict__ cand,
    const unsigned* __restrict__ ntc_in, const unsigned* __restrict__ rowMaxU,
    const float* __restrict__ Zr, float* __restrict__ colsum) {
  const unsigned total = ntc_in[1] < CAP_POOL ? ntc_in[1] : CAP_POOL;
  const unsigned stride = gridDim.x * 256;
  for (unsigned i = blockIdx.x * 256 + threadIdx.x; i < total; i += stride) {
    const unsigned long long e = cand[i];
    const unsigned pr = (unsigned)(e & 0xFFFFFFFu);
    const float t = __uint_as_float((unsigned)(e >> 32));
    const int n = (int)(pr >> 14);
    const float d = t - keyf(rowMaxU[n]);
    atomicAdd(&colsum[pr & 0x3FFFu], exp2f(d * L2E100) / Zr[n]);
  }
}

// ---------- fp64 re-rank of near-tie candidates (coalesced zT) ----------
__global__ __launch_bounds__(256) void k_refine(const float* __restrict__ zT,
    const float* __restrict__ emb, const unsigned* __restrict__ ntList,
    const unsigned* __restrict__ ntc, unsigned long long* __restrict__ rowkey) {
  const unsigned cnt = *ntc;
  const unsigned lim = cnt < NT_CAP ? cnt : NT_CAP;
  const int lane = threadIdx.x & 63, wv = threadIdx.x >> 6;
  for (unsigned slot = blockIdx.x * 4 + wv; slot < lim; slot += gridDim.x * 4) {
    const unsigned pr = ntList[slot];
    const int n = (int)(pr >> 14), k = (int)(pr & 0x3FFFu);
    double sz = 0.0, se = 0.0, sp = 0.0;
#pragma unroll
    for (int u = 0; u < CDIM / 64; ++u) {
      const int c = lane + u * 64;
      const double zv = (double)zT[(size_t)n * CDIM + c];
      const double ev = (double)emb[(size_t)k * CDIM + c];
      sz = fma(zv, zv, sz); se = fma(ev, ev, se); sp = fma(zv, ev, sp);
    }
    for (int off = 32; off; off >>= 1) {
      sz += __shfl_down(sz, off);
      se += __shfl_down(se, off);
      sp += __shfl_down(sp, off);
    }
    if (lane == 0) {
      const double nz = fmax(sqrt(sz), 1e-12);
      const double ne = fmax(sqrt(se), 1e-12);
      const double d = sz / (nz * nz) + se / (ne * ne) - 2.0 * sp / (nz * ne);
      const unsigned long long key =
          (((unsigned long long)(d * 140737488355328.0)) << 14) | (unsigned long long)k;
      atomicMin(&rowkey[n], key);
    }
  }
}

// ---------- z_q gather + idx extraction + sample entropy + vq sums ----------
__global__ __launch_bounds__(256) void k_zq(const unsigned short* __restrict__ A2,
    const unsigned short* __restrict__ B2, const unsigned long long* __restrict__ rowkey,
    const float* __restrict__ Zr, const float* __restrict__ Er,
    const long long* __restrict__ qids, int* __restrict__ idxI,
    float* __restrict__ outIdxF, float* __restrict__ outZ,
    float* __restrict__ scalars) {
  __shared__ int lidx[64];
  __shared__ unsigned short tile[64 * 264];
  __shared__ float sbuf[4];
  const int b = blockIdx.x >> 4, hw0 = (blockIdx.x & 15) * 64;
  const int tid = threadIdx.x;
  float ent = 0.f;
  if (tid < 64) {
    const int n = b * 1024 + hw0 + tid;
    const unsigned long long key = rowkey[n];
    const int k = (key != ~0ull) ? (int)(key & 0x3FFFull) : 0;
    lidx[tid] = k;
    idxI[n] = k;
    outIdxF[n] = (float)k;
    const float Z = Zr[n];
    ent = logf(Z) - Er[n] / Z;
  }
  const float es = blockReduceSum256(ent, sbuf);
  if (tid == 0) atomicAdd(&scalars[1], es);
  __syncthreads();
  const long long qid = qids[b];
  const int rr = tid >> 5, tt = tid & 31;
  float vq = 0.f;
#pragma unroll
  for (int it = 0; it < 8; ++it) {
    const int row = rr + 8 * it;
    const int token = b * 1024 + hw0 + row;
    union { uint4 v; unsigned short s[8]; } ev, zv;
    ev.v = *(const uint4*)&B2[(size_t)lidx[row] * CDIM + tt * 8];
    zv.v = *(const uint4*)&A2[(size_t)token * CDIM + tt * 8];
    *(uint4*)&tile[row * 264 + tt * 8] = ev.v;
    float dd = 0.f;
#pragma unroll
    for (int u = 0; u < 8; ++u) {
      const float d = bf2f(ev.s[u]) - bf2f(zv.s[u]);
      dd = fmaf(d, d, dd);
    }
    if ((long long)(row & 31) <= qid) vq += dd;
  }
  const float s = blockReduceSum256(vq, sbuf);
  if (tid == 0) atomicAdd(&scalars[0], s * (1.0f / 256.0f));
  __syncthreads();
  const int cg = tid >> 6, hwl = tid & 63;
#pragma unroll 8
  for (int i = 0; i < 64; ++i) {
    const int c = cg + i * 4;
    outZ[((size_t)(b * CDIM + c) << 10) + hw0 + hwl] = bf2f(tile[hwl * 264 + c]);
  }
}

__global__ __launch_bounds__(256) void k_avgent(const float* __restrict__ colsum,
                                                float* __restrict__ scalars) {
  __shared__ float sbuf[4];
  const int i = blockIdx.x * 256 + threadIdx.x;
  const float q = colsum[i] * (1.0f / (float)N_TOK);
  const float c = q * logf(q + 1e-5f);
  const float s = blockReduceSum256(c, sbuf);
  if (threadIdx.x == 0) atomicAdd(&scalars[2], s);
}

__global__ __launch_bounds__(256) void k_final(const int* __restrict__ idxI,
    const long long* __restrict__ qids, const float* __restrict__ scalars,
    float* __restrict__ out) {
  __shared__ float sbuf[4];
  const int tid = threadIdx.x;
  int cnt = 0;
  for (int p = tid; p < 1024; p += 256) {
    const int v = idxI[p];
    bool eq = true;
    for (int b = 1; b < 16; ++b) eq = eq && (idxI[b * 1024 + p] == v);
    cnt += eq ? 1 : 0;
  }
  const float dc = blockReduceSum256((float)cnt, sbuf);
  if (tid == 0) {
    float denom = 0.f;
    for (int b = 0; b < 16; ++b) denom += (float)(qids[b] + 1ll);
    out[4194304] = scalars[0] / denom;
    out[4194305] = 0.25f * scalars[0] / denom;
    out[4194306] = 0.1f * (scalars[1] * (1.0f / (float)N_TOK) + scalars[2]);
    out[4194307] = dc * (1.0f / 1024.0f);
  }
}

extern "C" void kernel_launch(void* const* d_in, const int* in_sizes, int n_in,
                              void* d_out, int out_size, void* d_ws, size_t ws_size,
                              hipStream_t stream) {
  const float*      z    = (const float*)d_in[0];
  const float*      emb  = (const float*)d_in[1];
  const long long*  qids = (const long long*)d_in[2];
  float* out = (float*)d_out;
  float* W   = (float*)d_ws;

  unsigned short* A2 = (unsigned short*)(W + OFF_A2);
  unsigned short* B2 = (unsigned short*)(W + OFF_B2);
  float* zT     = W + OFF_ZT;
  unsigned* rowMaxU = (unsigned*)(W + OFF_RMX);
  float* Zr     = W + OFF_ZR;
  float* Er     = W + OFF_ER;
  float* colsum = W + OFF_CS;
  float* scal   = W + OFF_SC;
  unsigned long long* rowkey = (unsigned long long*)(W + OFF_RK);
  unsigned* ntList = (unsigned*)(W + OFF_NT);
  unsigned* ntc    = (unsigned*)(W + OFF_NTC);
  int* idxI        = (int*)(W + OFF_IDX);
  unsigned long long* cand = (unsigned long long*)(W + OFF_CAND);

  k_zero    <<<dim3(64),          dim3(256), 0, stream>>>(colsum, scal, rowkey, ntc,
                                                          rowMaxU, Zr, Er);
  k_norm_emb<<<dim3(N_E / 4),     dim3(256), 0, stream>>>(emb, B2);
  k_norm_z  <<<dim3(256),         dim3(256), 0, stream>>>(z, A2, zT);
  k_pass1   <<<dim3(NCH, 256),    dim3(256), 0, stream>>>(A2, B2, cand, ntc, rowMaxU);
  k_cstat   <<<dim3(1024),        dim3(256), 0, stream>>>(cand, ntc, rowMaxU, Zr, Er,
                                                          ntList, ntc);
  k_ccol    <<<dim3(1024),        dim3(256), 0, stream>>>(cand, ntc, rowMaxU, Zr, colsum);
  k_refine  <<<dim3(1024),        dim3(256), 0, stream>>>(zT, emb, ntList, ntc, rowkey);
  k_zq      <<<dim3(256),         dim3(256), 0, stream>>>(A2, B2, rowkey, Zr, Er, qids,
                                                          idxI, out + 4194308, out, scal);
  k_avgent  <<<dim3(N_E / 256),   dim3(256), 0, stream>>>(colsum, scal);
  k_final   <<<dim3(1),           dim3(256), 0, stream>>>(idxI, qids, scal, out);
}

// Round 11
// 853.559 us; speedup vs baseline: 17.1922x; 17.1922x over previous
//
#include <hip/hip_runtime.h>
#include <math.h>

// Problem constants
#define N_TOK   16384
#define N_E     16384
#define CDIM    256
#define NCH     8
#define CHSZ    (N_E / NCH)      // 2048 codes per chunk
#define L2E100  144.26950408889634f   // 100 * log2(e)
#define DELTA_C 0.06f            // candidate window below running row max
#define EPS_NT  0.008f           // near-tie window for fp64 argmin re-rank
#define CAP_BLK 1536u            // per-block candidate cap (proven r6-r8)
#define NT_CAP  65536u
#define NBLK    2048

typedef __attribute__((ext_vector_type(8))) short short8;
typedef __attribute__((ext_vector_type(4))) float f32x4;

// ---- workspace layout (float offsets), total 42.7 MB (proven ws >= 52.5 MB) ----
#define OFF_A2   0u          // ushort[16384*256] bf16-hi normalized z (token-major)
#define OFF_B2   2097152u    // ushort[16384*256] bf16-hi normalized emb
#define OFF_RMX  4194304u    // 16384 u32 ordered-key row max
#define OFF_ZR   4210688u    // 16384 Z
#define OFF_ER   4227072u    // 16384 E (logit units)
#define OFF_CS   4243456u    // 16384 colsum
#define OFF_SC   4259840u    // 16 scalars
#define OFF_RK   4259856u    // 16384 u64 rowkey (8B aligned)
#define OFF_NT   4292624u    // 65536 u32 near-tie list
#define OFF_NTC  4358160u    // 16
#define OFF_CBC  4358176u    // 2048 per-block counts
#define OFF_IDX  4360224u    // 16384 int
#define OFF_CAND 4376608u    // u64[2048*1536] {f32 t | row<<14|col} (8B aligned)
// ends at 10,668,064 floats = 42.7 MB

__device__ __forceinline__ unsigned short f2bf(float x) {
  unsigned u = __float_as_uint(x);
  unsigned r = (u + 0x7fffu + ((u >> 16) & 1u)) >> 16;
  return (unsigned short)r;
}
__device__ __forceinline__ float bf2f(unsigned short h) {
  return __uint_as_float(((unsigned)h) << 16);
}
__device__ __forceinline__ unsigned fkey(float f) {      // order-preserving float->uint
  unsigned u = __float_as_uint(f);
  return (u & 0x80000000u) ? ~u : (u | 0x80000000u);
}
__device__ __forceinline__ float keyf(unsigned k) {
  return (k & 0x80000000u) ? __uint_as_float(k ^ 0x80000000u) : __uint_as_float(~k);
}

__device__ __forceinline__ void async_load16(const void* g, void* l) {
  __builtin_amdgcn_global_load_lds((const __attribute__((address_space(1))) void*)g,
                                   (__attribute__((address_space(3))) void*)l, 16, 0, 0);
}

__device__ __forceinline__ float blockReduceSum256(float v, float* sbuf) {
  __syncthreads();
  v += __shfl_down(v, 32);
  v += __shfl_down(v, 16);
  v += __shfl_down(v, 8);
  v += __shfl_down(v, 4);
  v += __shfl_down(v, 2);
  v += __shfl_down(v, 1);
  const int tid = threadIdx.x;
  if ((tid & 63) == 0) sbuf[tid >> 6] = v;
  __syncthreads();
  return sbuf[0] + sbuf[1] + sbuf[2] + sbuf[3];
}

__global__ __launch_bounds__(256) void k_zero(float* __restrict__ colsum,
                                              float* __restrict__ scalars,
                                              unsigned long long* __restrict__ rowkey,
                                              unsigned* __restrict__ ntc,
                                              unsigned* __restrict__ rowMaxU,
                                              float* __restrict__ Zr,
                                              float* __restrict__ Er) {
  const int i = blockIdx.x * 256 + threadIdx.x;
  colsum[i] = 0.f;
  rowkey[i] = ~0ull;
  rowMaxU[i] = 0u;
  Zr[i] = 0.f;
  Er[i] = 0.f;
  if (i < 16) { scalars[i] = 0.f; ntc[i] = 0u; }
}

// ---------- wave-per-row emb normalize ----------
__global__ __launch_bounds__(256) void k_norm_emb(const float* __restrict__ emb,
                                                  unsigned short* __restrict__ B2) {
  const int tid = threadIdx.x, lane = tid & 63, wv = tid >> 6;
  const int k = blockIdx.x * 4 + wv;
  const float4 v = *(const float4*)&emb[(size_t)k * CDIM + lane * 4];
  float ss = v.x * v.x + v.y * v.y + v.z * v.z + v.w * v.w;
#pragma unroll
  for (int off = 1; off < 64; off <<= 1) ss += __shfl_xor(ss, off);
  const float r = 1.0f / fmaxf(sqrtf(ss), 1e-12f);
  ushort4 o;
  o.x = f2bf(v.x * r); o.y = f2bf(v.y * r);
  o.z = f2bf(v.z * r); o.w = f2bf(v.w * r);
  *(ushort4*)&B2[(size_t)k * CDIM + lane * 4] = o;
}

// ---------- coalesced z normalize: block = (b, 64-hw tile), LDS transpose ----------
__global__ __launch_bounds__(256) void k_norm_z(const float* __restrict__ z,
                                                unsigned short* __restrict__ A2) {
  __shared__ float ssb[4][64];
  __shared__ float rn[64];
  __shared__ unsigned short tile[64 * 264];
  const int b = blockIdx.x >> 4, hw0 = (blockIdx.x & 15) * 64;
  const int tid = threadIdx.x, cg = tid >> 6, hwl = tid & 63;
  float ss = 0.f;
#pragma unroll 8
  for (int i = 0; i < 64; ++i) {
    const int c = cg + i * 4;
    const float x = z[((size_t)(b * CDIM + c) << 10) + hw0 + hwl];
    ss = fmaf(x, x, ss);
  }
  ssb[cg][hwl] = ss;
  __syncthreads();
  if (tid < 64) {
    const float t = ssb[0][tid] + ssb[1][tid] + ssb[2][tid] + ssb[3][tid];
    rn[tid] = 1.0f / fmaxf(sqrtf(t), 1e-12f);
  }
  __syncthreads();
  const float r = rn[hwl];
#pragma unroll 8
  for (int i = 0; i < 64; ++i) {
    const int c = cg + i * 4;
    const float x = z[((size_t)(b * CDIM + c) << 10) + hw0 + hwl];
    tile[hwl * 264 + c] = f2bf(x * r);
  }
  __syncthreads();
  const int rr = tid >> 5, tt = tid & 31;
#pragma unroll
  for (int it = 0; it < 8; ++it) {
    const int row = rr + 8 * it;
    const int token = b * 1024 + hw0 + row;
    const uint4 v = *(const uint4*)&tile[row * 264 + tt * 8];
    *(uint4*)&A2[(size_t)token * CDIM + tt * 8] = v;
  }
}

// ============ pass 1: r8 shape (2 blocks/CU), t = 2*dot, per-block candidates ============
__global__ __launch_bounds__(256, 2) void k_pass1(const unsigned short* __restrict__ A2,
    const unsigned short* __restrict__ B2,
    unsigned long long* __restrict__ cand, unsigned* __restrict__ cbc,
    unsigned* __restrict__ rowMaxU) {
  __shared__ alignas(16) unsigned short Af[64 * 256];     // 32 KB full-K A tile
  __shared__ alignas(16) unsigned short Bt[2][128 * 64];  // 2 x 16 KB B dbuf
  __shared__ unsigned smaxU[64];
  __shared__ unsigned lcnt;
  const int chunk = blockIdx.x, rt = blockIdx.y;
  const int r0 = rt * 64, k0 = chunk * CHSZ;
  const int blin = rt * NCH + chunk;
  const int tid = threadIdx.x, lane = tid & 63, w = tid >> 6;
  const int wrr = (w & 1) * 32, wc = (w >> 1) * 64;
  const int l15 = lane & 15, quad = lane >> 4;

  if (tid == 0) lcnt = 0u;
  if (tid < 64) smaxU[tid] = 0u;

  // stage full-K A tile (swizzle: position cg holds global group cg^(row&7))
#pragma unroll
  for (int i = 0; i < 8; ++i) {
    const int lin = i * 256 + tid;
    const int row = lin >> 5, cg = lin & 31;
    const int gcg = cg ^ (row & 7);
    async_load16((const char*)A2 + ((size_t)(r0 + row) * CDIM + gcg * 8) * 2,
                 (char*)Af + lin * 16);
  }
  // per-thread B staging bases
  const unsigned short* bsrc[4];
  unsigned bdst[4];
#pragma unroll
  for (int i = 0; i < 4; ++i) {
    const int lin = i * 256 + tid;
    const int row = lin >> 3, cg = lin & 7;
    const int gcg = cg ^ (row & 7);
    bsrc[i] = B2 + (size_t)(k0 + row) * CDIM + gcg * 8;
    bdst[i] = (unsigned)lin * 16u;
  }
#pragma unroll
  for (int i = 0; i < 4; ++i)
    async_load16(bsrc[i], (char*)Bt[0] + bdst[i]);

  // hoisted LDS read offsets
  int aoff[2][2], boff[4][2];
#pragma unroll
  for (int ti = 0; ti < 2; ++ti) {
    const int ar = wrr + ti * 16 + l15;
#pragma unroll
    for (int kk = 0; kk < 2; ++kk)
      aoff[ti][kk] = ar * 256 + ((((kk << 2) | quad) ^ (ar & 7)) * 8);
  }
#pragma unroll
  for (int tj = 0; tj < 4; ++tj) {
    const int br = wc + tj * 16 + l15;
#pragma unroll
    for (int kk = 0; kk < 2; ++kk)
      boff[tj][kk] = br * 64 + ((((kk << 2) | quad) ^ (br & 7)) * 8);
  }
  __syncthreads();

  f32x4 acc[2][4];

  for (int ct = 0; ct < 16; ++ct) {
#pragma unroll
    for (int ti = 0; ti < 2; ++ti)
#pragma unroll
      for (int tj = 0; tj < 4; ++tj) acc[ti][tj] = (f32x4){0.f, 0.f, 0.f, 0.f};

#pragma unroll
    for (int st = 0; st < 4; ++st) {
      if (!(ct == 15 && st == 3)) {
        const int noff = (st < 3) ? (st + 1) * 64 : 32768;
        char* dbuf = (char*)Bt[(st + 1) & 1];
#pragma unroll
        for (int i = 0; i < 4; ++i)
          async_load16(bsrc[i] + noff, dbuf + bdst[i]);
      }
      const unsigned short* bp = Bt[st & 1];
#pragma unroll
      for (int kk = 0; kk < 2; ++kk) {
        short8 af[2], bfr[4];
#pragma unroll
        for (int ti = 0; ti < 2; ++ti)
          af[ti] = *(const short8*)&Af[aoff[ti][kk] + st * 64];
#pragma unroll
        for (int tj = 0; tj < 4; ++tj)
          bfr[tj] = *(const short8*)&bp[boff[tj][kk]];
#pragma unroll
        for (int ti = 0; ti < 2; ++ti)
#pragma unroll
          for (int tj = 0; tj < 4; ++tj)
            acc[ti][tj] = __builtin_amdgcn_mfma_f32_16x16x32_bf16(af[ti], bfr[tj], acc[ti][tj], 0, 0, 0);
      }
      if (st == 3) {
        const int kb = k0 + ct * 128;
#pragma unroll
        for (int ti = 0; ti < 2; ++ti)
#pragma unroll
          for (int tj = 0; tj < 4; ++tj) {
            f32x4 a = acc[ti][tj];
#pragma unroll
            for (int r = 0; r < 4; ++r) a[r] = a[r] + a[r];   // t = 2*dot
            acc[ti][tj] = a;
          }
        // running row max -> LDS (atomic); NO barrier needed before reading:
        // any concurrently-read value v satisfies runmax_prev <= v <= final_max,
        // and threshold v-DELTA_C keeps a superset of {t >= final_max-DELTA_C}.
#pragma unroll
        for (int ti = 0; ti < 2; ++ti)
#pragma unroll
          for (int r = 0; r < 4; ++r) {
            float mt = fmaxf(fmaxf(acc[ti][0][r], acc[ti][1][r]),
                             fmaxf(acc[ti][2][r], acc[ti][3][r]));
            mt = fmaxf(mt, __shfl_xor(mt, 1));
            mt = fmaxf(mt, __shfl_xor(mt, 2));
            mt = fmaxf(mt, __shfl_xor(mt, 4));
            mt = fmaxf(mt, __shfl_xor(mt, 8));
            if (l15 == 0) atomicMax(&smaxU[wrr + ti * 16 + quad * 4 + r], fkey(mt));
          }
#pragma unroll
        for (int ti = 0; ti < 2; ++ti)
#pragma unroll
          for (int r = 0; r < 4; ++r) {
            const int rowloc = wrr + ti * 16 + quad * 4 + r;
            const float thr = keyf(smaxU[rowloc]) - DELTA_C;
            const unsigned rowg = (unsigned)(r0 + rowloc);
#pragma unroll
            for (int tj = 0; tj < 4; ++tj) {
              const float t = acc[ti][tj][r];
              if (t >= thr) {
                const unsigned slot = atomicAdd(&lcnt, 1u);
                if (slot < CAP_BLK) {
                  const unsigned pr = (rowg << 14) | (unsigned)(kb + wc + tj * 16 + l15);
                  cand[(size_t)blin * CAP_BLK + slot] =
                      ((unsigned long long)__float_as_uint(t) << 32) | pr;
                }
              }
            }
          }
      }
      __syncthreads();
    }
#pragma unroll
    for (int i = 0; i < 4; ++i) bsrc[i] += 32768;
  }
  if (tid < 64) atomicMax(&rowMaxU[r0 + tid], smaxU[tid]);
  if (tid == 0) cbc[blin] = lcnt < CAP_BLK ? lcnt : CAP_BLK;
}

// ---------- candidate pass: Z, E, near-tie list ----------
__global__ __launch_bounds__(256) void k_cstat(const unsigned long long* __restrict__ cand,
    const unsigned* __restrict__ cbc, const unsigned* __restrict__ rowMaxU,
    float* __restrict__ Zr, float* __restrict__ Er,
    unsigned* __restrict__ ntList, unsigned* __restrict__ ntc) {
  const int b = blockIdx.x;
  const unsigned cnt = cbc[b] < CAP_BLK ? cbc[b] : CAP_BLK;
  const int tid = threadIdx.x, lane = tid & 63;
  const unsigned lim = (cnt + 255u) & ~255u;
  for (unsigned i = tid; i < lim; i += 256u) {
    bool nt = false;
    unsigned pr = 0u;
    if (i < cnt) {
      const unsigned long long e = cand[(size_t)b * CAP_BLK + i];
      pr = (unsigned)(e & 0xFFFFFFFu);
      const float t = __uint_as_float((unsigned)(e >> 32));
      const int n = (int)(pr >> 14);
      const float d = t - keyf(rowMaxU[n]);
      const float ex = exp2f(d * L2E100);
      atomicAdd(&Zr[n], ex);
      atomicAdd(&Er[n], d * 100.0f * ex);
      nt = (d >= -EPS_NT);
    }
    const unsigned long long mask = __ballot(nt);
    const unsigned cw = (unsigned)__popcll(mask);
    unsigned base = 0u;
    if (lane == 0 && cw) base = atomicAdd(ntc, cw);
    base = __shfl((int)base, 0);
    if (nt) {
      const unsigned off = (unsigned)__popcll(mask & ((1ull << lane) - 1ull));
      const unsigned s = base + off;
      if (s < NT_CAP) ntList[s] = pr;
    }
  }
}

// ---------- candidate pass: colsum ----------
__global__ __launch_bounds__(256) void k_ccol(const unsigned long long* __restrict__ cand,
    const unsigned* __restrict__ cbc, const unsigned* __restrict__ rowMaxU,
    const float* __restrict__ Zr, float* __restrict__ colsum) {
  const int b = blockIdx.x;
  const unsigned cnt = cbc[b] < CAP_BLK ? cbc[b] : CAP_BLK;
  for (unsigned i = threadIdx.x; i < cnt; i += 256u) {
    const unsigned long long e = cand[(size_t)b * CAP_BLK + i];
    const unsigned pr = (unsigned)(e & 0xFFFFFFFu);
    const float t = __uint_as_float((unsigned)(e >> 32));
    const int n = (int)(pr >> 14);
    const float d = t - keyf(rowMaxU[n]);
    atomicAdd(&colsum[pr & 0x3FFFu], exp2f(d * L2E100) / Zr[n]);
  }
}

// ---------- fp64 re-rank of near-tie candidates ----------
__global__ __launch_bounds__(256) void k_refine(const float* __restrict__ z,
    const float* __restrict__ emb, const unsigned* __restrict__ ntList,
    const unsigned* __restrict__ ntc, unsigned long long* __restrict__ rowkey) {
  const unsigned cnt = *ntc;
  const unsigned lim = cnt < NT_CAP ? cnt : NT_CAP;
  const int lane = threadIdx.x & 63, wv = threadIdx.x >> 6;
  for (unsigned slot = blockIdx.x * 4 + wv; slot < lim; slot += gridDim.x * 4) {
    const unsigned pr = ntList[slot];
    const int n = (int)(pr >> 14), k = (int)(pr & 0x3FFFu);
    const int b = n >> 10, hw = n & 1023;
    double sz = 0.0, se = 0.0, sp = 0.0;
#pragma unroll
    for (int u = 0; u < CDIM / 64; ++u) {
      const int c = lane + u * 64;
      const double zv = (double)z[((size_t)(b * CDIM + c) << 10) + hw];
      const double ev = (double)emb[(size_t)k * CDIM + c];
      sz = fma(zv, zv, sz); se = fma(ev, ev, se); sp = fma(zv, ev, sp);
    }
    for (int off = 32; off; off >>= 1) {
      sz += __shfl_down(sz, off);
      se += __shfl_down(se, off);
      sp += __shfl_down(sp, off);
    }
    if (lane == 0) {
      const double nz = fmax(sqrt(sz), 1e-12);
      const double ne = fmax(sqrt(se), 1e-12);
      const double d = sz / (nz * nz) + se / (ne * ne) - 2.0 * sp / (nz * ne);
      const unsigned long long key =
          (((unsigned long long)(d * 140737488355328.0)) << 14) | (unsigned long long)k;
      atomicMin(&rowkey[n], key);
    }
  }
}

// ---------- z_q gather + idx extraction + sample entropy + vq sums ----------
__global__ __launch_bounds__(256) void k_zq(const unsigned short* __restrict__ A2,
    const unsigned short* __restrict__ B2, const unsigned long long* __restrict__ rowkey,
    const float* __restrict__ Zr, const float* __restrict__ Er,
    const long long* __restrict__ qids, int* __restrict__ idxI,
    float* __restrict__ outIdxF, float* __restrict__ outZ,
    float* __restrict__ scalars) {
  __shared__ int lidx[64];
  __shared__ unsigned short tile[64 * 264];
  __shared__ float sbuf[4];
  const int b = blockIdx.x >> 4, hw0 = (blockIdx.x & 15) * 64;
  const int tid = threadIdx.x;
  float ent = 0.f;
  if (tid < 64) {
    const int n = b * 1024 + hw0 + tid;
    const unsigned long long key = rowkey[n];
    const int k = (key != ~0ull) ? (int)(key & 0x3FFFull) : 0;
    lidx[tid] = k;
    idxI[n] = k;
    outIdxF[n] = (float)k;
    const float Z = Zr[n];
    ent = logf(Z) - Er[n] / Z;
  }
  const float es = blockReduceSum256(ent, sbuf);
  if (tid == 0) atomicAdd(&scalars[1], es);
  __syncthreads();
  const long long qid = qids[b];
  const int rr = tid >> 5, tt = tid & 31;
  float vq = 0.f;
#pragma unroll
  for (int it = 0; it < 8; ++it) {
    const int row = rr + 8 * it;
    const int token = b * 1024 + hw0 + row;
    union { uint4 v; unsigned short s[8]; } ev, zv;
    ev.v = *(const uint4*)&B2[(size_t)lidx[row] * CDIM + tt * 8];
    zv.v = *(const uint4*)&A2[(size_t)token * CDIM + tt * 8];
    *(uint4*)&tile[row * 264 + tt * 8] = ev.v;
    float dd = 0.f;
#pragma unroll
    for (int u = 0; u < 8; ++u) {
      const float d = bf2f(ev.s[u]) - bf2f(zv.s[u]);
      dd = fmaf(d, d, dd);
    }
    if ((long long)(row & 31) <= qid) vq += dd;
  }
  const float s = blockReduceSum256(vq, sbuf);
  if (tid == 0) atomicAdd(&scalars[0], s * (1.0f / 256.0f));
  __syncthreads();
  const int cg = tid >> 6, hwl = tid & 63;
#pragma unroll 8
  for (int i = 0; i < 64; ++i) {
    const int c = cg + i * 4;
    outZ[((size_t)(b * CDIM + c) << 10) + hw0 + hwl] = bf2f(tile[hwl * 264 + c]);
  }
}

__global__ __launch_bounds__(256) void k_avgent(const float* __restrict__ colsum,
                                                float* __restrict__ scalars) {
  __shared__ float sbuf[4];
  const int i = blockIdx.x * 256 + threadIdx.x;
  const float q = colsum[i] * (1.0f / (float)N_TOK);
  const float c = q * logf(q + 1e-5f);
  const float s = blockReduceSum256(c, sbuf);
  if (threadIdx.x == 0) atomicAdd(&scalars[2], s);
}

__global__ __launch_bounds__(256) void k_final(const int* __restrict__ idxI,
    const long long* __restrict__ qids, const float* __restrict__ scalars,
    float* __restrict__ out) {
  __shared__ float sbuf[4];
  const int tid = threadIdx.x;
  int cnt = 0;
  for (int p = tid; p < 1024; p += 256) {
    const int v = idxI[p];
    bool eq = true;
    for (int b = 1; b < 16; ++b) eq = eq && (idxI[b * 1024 + p] == v);
    cnt += eq ? 1 : 0;
  }
  const float dc = blockReduceSum256((float)cnt, sbuf);
  if (tid == 0) {
    float denom = 0.f;
    for (int b = 0; b < 16; ++b) denom += (float)(qids[b] + 1ll);
    out[4194304] = scalars[0] / denom;
    out[4194305] = 0.25f * scalars[0] / denom;
    out[4194306] = 0.1f * (scalars[1] * (1.0f / (float)N_TOK) + scalars[2]);
    out[4194307] = dc * (1.0f / 1024.0f);
  }
}

extern "C" void kernel_launch(void* const* d_in, const int* in_sizes, int n_in,
                              void* d_out, int out_size, void* d_ws, size_t ws_size,
                              hipStream_t stream) {
  const float*      z    = (const float*)d_in[0];
  const float*      emb  = (const float*)d_in[1];
  const long long*  qids = (const long long*)d_in[2];
  float* out = (float*)d_out;
  float* W   = (float*)d_ws;

  unsigned short* A2 = (unsigned short*)(W + OFF_A2);
  unsigned short* B2 = (unsigned short*)(W + OFF_B2);
  unsigned* rowMaxU = (unsigned*)(W + OFF_RMX);
  float* Zr     = W + OFF_ZR;
  float* Er     = W + OFF_ER;
  float* colsum = W + OFF_CS;
  float* scal   = W + OFF_SC;
  unsigned long long* rowkey = (unsigned long long*)(W + OFF_RK);
  unsigned* ntList = (unsigned*)(W + OFF_NT);
  unsigned* ntc    = (unsigned*)(W + OFF_NTC);
  unsigned* cbc    = (unsigned*)(W + OFF_CBC);
  int* idxI        = (int*)(W + OFF_IDX);
  unsigned long long* cand = (unsigned long long*)(W + OFF_CAND);

  k_zero    <<<dim3(64),          dim3(256), 0, stream>>>(colsum, scal, rowkey, ntc,
                                                          rowMaxU, Zr, Er);
  k_norm_emb<<<dim3(N_E / 4),     dim3(256), 0, stream>>>(emb, B2);
  k_norm_z  <<<dim3(256),         dim3(256), 0, stream>>>(z, A2);
  k_pass1   <<<dim3(NCH, 256),    dim3(256), 0, stream>>>(A2, B2, cand, cbc, rowMaxU);
  k_cstat   <<<dim3(NBLK),        dim3(256), 0, stream>>>(cand, cbc, rowMaxU, Zr, Er,
                                                          ntList, ntc);
  k_ccol    <<<dim3(NBLK),        dim3(256), 0, stream>>>(cand, cbc, rowMaxU, Zr, colsum);
  k_refine  <<<dim3(1024),        dim3(256), 0, stream>>>(z, emb, ntList, ntc, rowkey);
  k_zq      <<<dim3(256),         dim3(256), 0, stream>>>(A2, B2, rowkey, Zr, Er, qids,
                                                          idxI, out + 4194308, out, scal);
  k_avgent  <<<dim3(N_E / 256),   dim3(256), 0, stream>>>(colsum, scal);
  k_final   <<<dim3(1),           dim3(256), 0, stream>>>(idxI, qids, scal, out);
}

// Round 12
// 748.872 us; speedup vs baseline: 19.5956x; 1.1398x over previous
//
#include <hip/hip_runtime.h>
#include <math.h>

// Problem constants
#define N_TOK   16384
#define N_E     16384
#define CDIM    256
#define NCH     8
#define CHSZ    (N_E / NCH)      // 2048 codes per chunk
#define L2E100  144.26950408889634f   // 100 * log2(e)
#define DELTA_C 0.06f            // candidate window below running row max
#define EPS_NT  0.008f           // near-tie window for fp64 argmin re-rank
#define CAP_BLK 1536u            // per-block candidate cap (proven r6-r11)
#define NT_CAP  65536u
#define NBLK    2048

typedef __attribute__((ext_vector_type(8))) short short8;
typedef __attribute__((ext_vector_type(4))) float f32x4;

// ---- workspace layout (float offsets), ~42.7 MB (proven ws >= 52.5 MB) ----
#define OFF_A2   0u          // ushort[16384*256] bf16-hi normalized z (token-major)
#define OFF_B2   2097152u    // ushort[16384*256] bf16-hi normalized emb
#define OFF_RMX  4194304u    // 16384 u32 ordered-key row max
#define OFF_CS   4243456u    // 16384 colsum
#define OFF_SC   4259840u    // 16 scalars
#define OFF_RK   4259856u    // 16384 u64 rowkey (8B aligned)
#define OFF_NT   4292624u    // 65536 u32 near-tie list
#define OFF_NTC  4358160u    // 16
#define OFF_CBC  4358176u    // 2048 per-block counts
#define OFF_IDX  4360224u    // 16384 int
#define OFF_CAND 4376608u    // u64[2048*1536] {f32 t | row<<14|col} (8B aligned)

__device__ __forceinline__ unsigned short f2bf(float x) {
  unsigned u = __float_as_uint(x);
  unsigned r = (u + 0x7fffu + ((u >> 16) & 1u)) >> 16;
  return (unsigned short)r;
}
__device__ __forceinline__ float bf2f(unsigned short h) {
  return __uint_as_float(((unsigned)h) << 16);
}
__device__ __forceinline__ unsigned fkey(float f) {      // order-preserving float->uint
  unsigned u = __float_as_uint(f);
  return (u & 0x80000000u) ? ~u : (u | 0x80000000u);
}
__device__ __forceinline__ float keyf(unsigned k) {
  return (k & 0x80000000u) ? __uint_as_float(k ^ 0x80000000u) : __uint_as_float(~k);
}

__device__ __forceinline__ void async_load16(const void* g, void* l) {
  __builtin_amdgcn_global_load_lds((const __attribute__((address_space(1))) void*)g,
                                   (__attribute__((address_space(3))) void*)l, 16, 0, 0);
}

__device__ __forceinline__ float blockReduceSum256(float v, float* sbuf) {
  __syncthreads();
  v += __shfl_down(v, 32);
  v += __shfl_down(v, 16);
  v += __shfl_down(v, 8);
  v += __shfl_down(v, 4);
  v += __shfl_down(v, 2);
  v += __shfl_down(v, 1);
  const int tid = threadIdx.x;
  if ((tid & 63) == 0) sbuf[tid >> 6] = v;
  __syncthreads();
  return sbuf[0] + sbuf[1] + sbuf[2] + sbuf[3];
}

__global__ __launch_bounds__(256) void k_zero(float* __restrict__ colsum,
                                              float* __restrict__ scalars,
                                              unsigned long long* __restrict__ rowkey,
                                              unsigned* __restrict__ ntc,
                                              unsigned* __restrict__ rowMaxU) {
  const int i = blockIdx.x * 256 + threadIdx.x;
  colsum[i] = 0.f;
  rowkey[i] = ~0ull;
  rowMaxU[i] = 0u;
  if (i < 16) { scalars[i] = 0.f; ntc[i] = 0u; }
}

// ---------- wave-per-row emb normalize ----------
__global__ __launch_bounds__(256) void k_norm_emb(const float* __restrict__ emb,
                                                  unsigned short* __restrict__ B2) {
  const int tid = threadIdx.x, lane = tid & 63, wv = tid >> 6;
  const int k = blockIdx.x * 4 + wv;
  const float4 v = *(const float4*)&emb[(size_t)k * CDIM + lane * 4];
  float ss = v.x * v.x + v.y * v.y + v.z * v.z + v.w * v.w;
#pragma unroll
  for (int off = 1; off < 64; off <<= 1) ss += __shfl_xor(ss, off);
  const float r = 1.0f / fmaxf(sqrtf(ss), 1e-12f);
  ushort4 o;
  o.x = f2bf(v.x * r); o.y = f2bf(v.y * r);
  o.z = f2bf(v.z * r); o.w = f2bf(v.w * r);
  *(ushort4*)&B2[(size_t)k * CDIM + lane * 4] = o;
}

// ---------- coalesced z normalize: block = (b, 64-hw tile), LDS transpose ----------
__global__ __launch_bounds__(256) void k_norm_z(const float* __restrict__ z,
                                                unsigned short* __restrict__ A2) {
  __shared__ float ssb[4][64];
  __shared__ float rn[64];
  __shared__ unsigned short tile[64 * 264];
  const int b = blockIdx.x >> 4, hw0 = (blockIdx.x & 15) * 64;
  const int tid = threadIdx.x, cg = tid >> 6, hwl = tid & 63;
  float ss = 0.f;
#pragma unroll 8
  for (int i = 0; i < 64; ++i) {
    const int c = cg + i * 4;
    const float x = z[((size_t)(b * CDIM + c) << 10) + hw0 + hwl];
    ss = fmaf(x, x, ss);
  }
  ssb[cg][hwl] = ss;
  __syncthreads();
  if (tid < 64) {
    const float t = ssb[0][tid] + ssb[1][tid] + ssb[2][tid] + ssb[3][tid];
    rn[tid] = 1.0f / fmaxf(sqrtf(t), 1e-12f);
  }
  __syncthreads();
  const float r = rn[hwl];
#pragma unroll 8
  for (int i = 0; i < 64; ++i) {
    const int c = cg + i * 4;
    const float x = z[((size_t)(b * CDIM + c) << 10) + hw0 + hwl];
    tile[hwl * 264 + c] = f2bf(x * r);
  }
  __syncthreads();
  const int rr = tid >> 5, tt = tid & 31;
#pragma unroll
  for (int it = 0; it < 8; ++it) {
    const int row = rr + 8 * it;
    const int token = b * 1024 + hw0 + row;
    const uint4 v = *(const uint4*)&tile[row * 264 + tt * 8];
    *(uint4*)&A2[(size_t)token * CDIM + tt * 8] = v;
  }
}

// ============ pass 1: r8-proven shape (2 blocks/CU), t = 2*dot ============
__global__ __launch_bounds__(256, 2) void k_pass1(const unsigned short* __restrict__ A2,
    const unsigned short* __restrict__ B2,
    unsigned long long* __restrict__ cand, unsigned* __restrict__ cbc,
    unsigned* __restrict__ rowMaxU) {
  __shared__ alignas(16) unsigned short Af[64 * 256];     // 32 KB full-K A tile
  __shared__ alignas(16) unsigned short Bt[2][128 * 64];  // 2 x 16 KB B dbuf
  __shared__ unsigned smaxU[64];
  __shared__ unsigned lcnt;
  const int chunk = blockIdx.x, rt = blockIdx.y;
  const int r0 = rt * 64, k0 = chunk * CHSZ;
  const int blin = rt * NCH + chunk;
  const int tid = threadIdx.x, lane = tid & 63, w = tid >> 6;
  const int wrr = (w & 1) * 32, wc = (w >> 1) * 64;
  const int l15 = lane & 15, quad = lane >> 4;

  if (tid == 0) lcnt = 0u;
  if (tid < 64) smaxU[tid] = 0u;

  // stage full-K A tile (swizzle: position cg holds global group cg^(row&7))
#pragma unroll
  for (int i = 0; i < 8; ++i) {
    const int lin = i * 256 + tid;
    const int row = lin >> 5, cg = lin & 31;
    const int gcg = cg ^ (row & 7);
    async_load16((const char*)A2 + ((size_t)(r0 + row) * CDIM + gcg * 8) * 2,
                 (char*)Af + lin * 16);
  }
  // per-thread B staging bases
  const unsigned short* bsrc[4];
  unsigned bdst[4];
#pragma unroll
  for (int i = 0; i < 4; ++i) {
    const int lin = i * 256 + tid;
    const int row = lin >> 3, cg = lin & 7;
    const int gcg = cg ^ (row & 7);
    bsrc[i] = B2 + (size_t)(k0 + row) * CDIM + gcg * 8;
    bdst[i] = (unsigned)lin * 16u;
  }
#pragma unroll
  for (int i = 0; i < 4; ++i)
    async_load16(bsrc[i], (char*)Bt[0] + bdst[i]);

  // hoisted LDS read offsets
  int aoff[2][2], boff[4][2];
#pragma unroll
  for (int ti = 0; ti < 2; ++ti) {
    const int ar = wrr + ti * 16 + l15;
#pragma unroll
    for (int kk = 0; kk < 2; ++kk)
      aoff[ti][kk] = ar * 256 + ((((kk << 2) | quad) ^ (ar & 7)) * 8);
  }
#pragma unroll
  for (int tj = 0; tj < 4; ++tj) {
    const int br = wc + tj * 16 + l15;
#pragma unroll
    for (int kk = 0; kk < 2; ++kk)
      boff[tj][kk] = br * 64 + ((((kk << 2) | quad) ^ (br & 7)) * 8);
  }
  __syncthreads();

  f32x4 acc[2][4];

  for (int ct = 0; ct < 16; ++ct) {
#pragma unroll
    for (int ti = 0; ti < 2; ++ti)
#pragma unroll
      for (int tj = 0; tj < 4; ++tj) acc[ti][tj] = (f32x4){0.f, 0.f, 0.f, 0.f};

#pragma unroll
    for (int st = 0; st < 4; ++st) {
      if (!(ct == 15 && st == 3)) {
        const int noff = (st < 3) ? (st + 1) * 64 : 32768;
        char* dbuf = (char*)Bt[(st + 1) & 1];
#pragma unroll
        for (int i = 0; i < 4; ++i)
          async_load16(bsrc[i] + noff, dbuf + bdst[i]);
      }
      const unsigned short* bp = Bt[st & 1];
#pragma unroll
      for (int kk = 0; kk < 2; ++kk) {
        short8 af[2], bfr[4];
#pragma unroll
        for (int ti = 0; ti < 2; ++ti)
          af[ti] = *(const short8*)&Af[aoff[ti][kk] + st * 64];
#pragma unroll
        for (int tj = 0; tj < 4; ++tj)
          bfr[tj] = *(const short8*)&bp[boff[tj][kk]];
#pragma unroll
        for (int ti = 0; ti < 2; ++ti)
#pragma unroll
          for (int tj = 0; tj < 4; ++tj)
            acc[ti][tj] = __builtin_amdgcn_mfma_f32_16x16x32_bf16(af[ti], bfr[tj], acc[ti][tj], 0, 0, 0);
      }
      if (st == 3) {
        const int kb = k0 + ct * 128;
#pragma unroll
        for (int ti = 0; ti < 2; ++ti)
#pragma unroll
          for (int tj = 0; tj < 4; ++tj) {
            f32x4 a = acc[ti][tj];
#pragma unroll
            for (int r = 0; r < 4; ++r) a[r] = a[r] + a[r];   // t = 2*dot
            acc[ti][tj] = a;
          }
#pragma unroll
        for (int ti = 0; ti < 2; ++ti)
#pragma unroll
          for (int r = 0; r < 4; ++r) {
            float mt = fmaxf(fmaxf(acc[ti][0][r], acc[ti][1][r]),
                             fmaxf(acc[ti][2][r], acc[ti][3][r]));
            mt = fmaxf(mt, __shfl_xor(mt, 1));
            mt = fmaxf(mt, __shfl_xor(mt, 2));
            mt = fmaxf(mt, __shfl_xor(mt, 4));
            mt = fmaxf(mt, __shfl_xor(mt, 8));
            if (l15 == 0) atomicMax(&smaxU[wrr + ti * 16 + quad * 4 + r], fkey(mt));
          }
        __syncthreads();   // r8-proven: all waves' maxes visible -> tight threshold
#pragma unroll
        for (int ti = 0; ti < 2; ++ti)
#pragma unroll
          for (int r = 0; r < 4; ++r) {
            const int rowloc = wrr + ti * 16 + quad * 4 + r;
            const float thr = keyf(smaxU[rowloc]) - DELTA_C;
            const unsigned rowg = (unsigned)(r0 + rowloc);
#pragma unroll
            for (int tj = 0; tj < 4; ++tj) {
              const float t = acc[ti][tj][r];
              if (t >= thr) {
                const unsigned slot = atomicAdd(&lcnt, 1u);
                if (slot < CAP_BLK) {
                  const unsigned pr = (rowg << 14) | (unsigned)(kb + wc + tj * 16 + l15);
                  cand[(size_t)blin * CAP_BLK + slot] =
                      ((unsigned long long)__float_as_uint(t) << 32) | pr;
                }
              }
            }
          }
      }
      __syncthreads();
    }
#pragma unroll
    for (int i = 0; i < 4; ++i) bsrc[i] += 32768;
  }
  if (tid < 64) atomicMax(&rowMaxU[r0 + tid], smaxU[tid]);
  if (tid == 0) cbc[blin] = lcnt < CAP_BLK ? lcnt : CAP_BLK;
}

// ---------- fused candidate processing: block = rt, LDS-local Z/E ----------
// Candidates for rows [rt*64, rt*64+64) live exactly in blocks [rt*8, rt*8+8).
__global__ __launch_bounds__(256) void k_cstat2(const unsigned long long* __restrict__ cand,
    const unsigned* __restrict__ cbc, const unsigned* __restrict__ rowMaxU,
    float* __restrict__ colsum, unsigned* __restrict__ ntList,
    unsigned* __restrict__ ntc, float* __restrict__ scalars) {
  __shared__ float lM[64], lZ[64], lE[64], lIZ[64];
  __shared__ float sbuf[4];
  const int rt = blockIdx.x, r0 = rt * 64;
  const int tid = threadIdx.x, lane = tid & 63;
  if (tid < 64) {
    lM[tid] = keyf(rowMaxU[r0 + tid]);
    lZ[tid] = 0.f; lE[tid] = 0.f;
  }
  __syncthreads();
  // phase 1: Z, E
  for (int sub = 0; sub < NCH; ++sub) {
    const int blin = rt * NCH + sub;
    const unsigned cnt = cbc[blin] < CAP_BLK ? cbc[blin] : CAP_BLK;
    for (unsigned i = tid; i < cnt; i += 256u) {
      const unsigned long long e = cand[(size_t)blin * CAP_BLK + i];
      const unsigned pr = (unsigned)(e & 0xFFFFFFFu);
      const float t = __uint_as_float((unsigned)(e >> 32));
      const int rowl = (int)((pr >> 14) & 63u);
      const float d = t - lM[rowl];
      const float ex = exp2f(d * L2E100);
      atomicAdd(&lZ[rowl], ex);
      atomicAdd(&lE[rowl], d * 100.0f * ex);
    }
  }
  __syncthreads();
  // per-row finalize + block-local entropy reduction
  float ent = 0.f;
  if (tid < 64) {
    const float Z = lZ[tid];
    lIZ[tid] = 1.0f / Z;
    ent = logf(Z) - lE[tid] / Z;
  }
  const float es = blockReduceSum256(ent, sbuf);
  if (tid == 0) atomicAdd(&scalars[1], es);
  __syncthreads();
  // phase 2: colsum + near-tie list
  for (int sub = 0; sub < NCH; ++sub) {
    const int blin = rt * NCH + sub;
    const unsigned cnt = cbc[blin] < CAP_BLK ? cbc[blin] : CAP_BLK;
    const unsigned lim = (cnt + 255u) & ~255u;
    for (unsigned i = tid; i < lim; i += 256u) {
      bool nt = false;
      unsigned pr = 0u;
      if (i < cnt) {
        const unsigned long long e = cand[(size_t)blin * CAP_BLK + i];
        pr = (unsigned)(e & 0xFFFFFFFu);
        const float t = __uint_as_float((unsigned)(e >> 32));
        const int rowl = (int)((pr >> 14) & 63u);
        const float d = t - lM[rowl];
        atomicAdd(&colsum[pr & 0x3FFFu], exp2f(d * L2E100) * lIZ[rowl]);
        nt = (d >= -EPS_NT);
      }
      const unsigned long long mask = __ballot(nt);
      const unsigned cw = (unsigned)__popcll(mask);
      unsigned base = 0u;
      if (lane == 0 && cw) base = atomicAdd(ntc, cw);
      base = __shfl((int)base, 0);
      if (nt) {
        const unsigned off = (unsigned)__popcll(mask & ((1ull << lane) - 1ull));
        const unsigned s = base + off;
        if (s < NT_CAP) ntList[s] = pr;
      }
    }
  }
}

// ---------- fp64 re-rank of near-tie candidates ----------
__global__ __launch_bounds__(256) void k_refine(const float* __restrict__ z,
    const float* __restrict__ emb, const unsigned* __restrict__ ntList,
    const unsigned* __restrict__ ntc, unsigned long long* __restrict__ rowkey) {
  const unsigned cnt = *ntc;
  const unsigned lim = cnt < NT_CAP ? cnt : NT_CAP;
  const int lane = threadIdx.x & 63, wv = threadIdx.x >> 6;
  for (unsigned slot = blockIdx.x * 4 + wv; slot < lim; slot += gridDim.x * 4) {
    const unsigned pr = ntList[slot];
    const int n = (int)(pr >> 14), k = (int)(pr & 0x3FFFu);
    const int b = n >> 10, hw = n & 1023;
    double sz = 0.0, se = 0.0, sp = 0.0;
#pragma unroll
    for (int u = 0; u < CDIM / 64; ++u) {
      const int c = lane + u * 64;
      const double zv = (double)z[((size_t)(b * CDIM + c) << 10) + hw];
      const double ev = (double)emb[(size_t)k * CDIM + c];
      sz = fma(zv, zv, sz); se = fma(ev, ev, se); sp = fma(zv, ev, sp);
    }
    for (int off = 32; off; off >>= 1) {
      sz += __shfl_down(sz, off);
      se += __shfl_down(se, off);
      sp += __shfl_down(sp, off);
    }
    if (lane == 0) {
      const double nz = fmax(sqrt(sz), 1e-12);
      const double ne = fmax(sqrt(se), 1e-12);
      const double d = sz / (nz * nz) + se / (ne * ne) - 2.0 * sp / (nz * ne);
      const unsigned long long key =
          (((unsigned long long)(d * 140737488355328.0)) << 14) | (unsigned long long)k;
      atomicMin(&rowkey[n], key);
    }
  }
}

// ---------- z_q gather + idx extraction + vq sums ----------
__global__ __launch_bounds__(256) void k_zq(const unsigned short* __restrict__ A2,
    const unsigned short* __restrict__ B2, const unsigned long long* __restrict__ rowkey,
    const long long* __restrict__ qids, int* __restrict__ idxI,
    float* __restrict__ outIdxF, float* __restrict__ outZ,
    float* __restrict__ scalars) {
  __shared__ int lidx[64];
  __shared__ unsigned short tile[64 * 264];
  __shared__ float sbuf[4];
  const int b = blockIdx.x >> 4, hw0 = (blockIdx.x & 15) * 64;
  const int tid = threadIdx.x;
  if (tid < 64) {
    const int n = b * 1024 + hw0 + tid;
    const unsigned long long key = rowkey[n];
    const int k = (key != ~0ull) ? (int)(key & 0x3FFFull) : 0;
    lidx[tid] = k;
    idxI[n] = k;
    outIdxF[n] = (float)k;
  }
  __syncthreads();
  const long long qid = qids[b];
  const int rr = tid >> 5, tt = tid & 31;
  float vq = 0.f;
#pragma unroll
  for (int it = 0; it < 8; ++it) {
    const int row = rr + 8 * it;
    const int token = b * 1024 + hw0 + row;
    union { uint4 v; unsigned short s[8]; } ev, zv;
    ev.v = *(const uint4*)&B2[(size_t)lidx[row] * CDIM + tt * 8];
    zv.v = *(const uint4*)&A2[(size_t)token * CDIM + tt * 8];
    *(uint4*)&tile[row * 264 + tt * 8] = ev.v;
    float dd = 0.f;
#pragma unroll
    for (int u = 0; u < 8; ++u) {
      const float d = bf2f(ev.s[u]) - bf2f(zv.s[u]);
      dd = fmaf(d, d, dd);
    }
    if ((long long)(row & 31) <= qid) vq += dd;
  }
  const float s = blockReduceSum256(vq, sbuf);
  if (tid == 0) atomicAdd(&scalars[0], s * (1.0f / 256.0f));
  __syncthreads();
  const int cg = tid >> 6, hwl = tid & 63;
#pragma unroll 8
  for (int i = 0; i < 64; ++i) {
    const int c = cg + i * 4;
    outZ[((size_t)(b * CDIM + c) << 10) + hw0 + hwl] = bf2f(tile[hwl * 264 + c]);
  }
}

// ---------- final: avg-entropy from colsum + dead-code + scalar outputs ----------
__global__ __launch_bounds__(256) void k_final(const int* __restrict__ idxI,
    const long long* __restrict__ qids, const float* __restrict__ colsum,
    const float* __restrict__ scalars, float* __restrict__ out) {
  __shared__ float sbuf[4];
  const int tid = threadIdx.x;
  float ae = 0.f;
  for (int i = tid; i < N_E; i += 256) {
    const float q = colsum[i] * (1.0f / (float)N_TOK);
    ae += q * logf(q + 1e-5f);
  }
  const float aes = blockReduceSum256(ae, sbuf);   // = -avg_entropy
  int cnt = 0;
  for (int p = tid; p < 1024; p += 256) {
    const int v = idxI[p];
    bool eq = true;
    for (int b = 1; b < 16; ++b) eq = eq && (idxI[b * 1024 + p] == v);
    cnt += eq ? 1 : 0;
  }
  const float dc = blockReduceSum256((float)cnt, sbuf);
  if (tid == 0) {
    float denom = 0.f;
    for (int b = 0; b < 16; ++b) denom += (float)(qids[b] + 1ll);
    out[4194304] = scalars[0] / denom;
    out[4194305] = 0.25f * scalars[0] / denom;
    out[4194306] = 0.1f * (scalars[1] * (1.0f / (float)N_TOK) + aes);
    out[4194307] = dc * (1.0f / 1024.0f);
  }
}

extern "C" void kernel_launch(void* const* d_in, const int* in_sizes, int n_in,
                              void* d_out, int out_size, void* d_ws, size_t ws_size,
                              hipStream_t stream) {
  const float*      z    = (const float*)d_in[0];
  const float*      emb  = (const float*)d_in[1];
  const long long*  qids = (const long long*)d_in[2];
  float* out = (float*)d_out;
  float* W   = (float*)d_ws;

  unsigned short* A2 = (unsigned short*)(W + OFF_A2);
  unsigned short* B2 = (unsigned short*)(W + OFF_B2);
  unsigned* rowMaxU = (unsigned*)(W + OFF_RMX);
  float* colsum = W + OFF_CS;
  float* scal   = W + OFF_SC;
  unsigned long long* rowkey = (unsigned long long*)(W + OFF_RK);
  unsigned* ntList = (unsigned*)(W + OFF_NT);
  unsigned* ntc    = (unsigned*)(W + OFF_NTC);
  unsigned* cbc    = (unsigned*)(W + OFF_CBC);
  int* idxI        = (int*)(W + OFF_IDX);
  unsigned long long* cand = (unsigned long long*)(W + OFF_CAND);

  k_zero    <<<dim3(64),          dim3(256), 0, stream>>>(colsum, scal, rowkey, ntc, rowMaxU);
  k_norm_emb<<<dim3(N_E / 4),     dim3(256), 0, stream>>>(emb, B2);
  k_norm_z  <<<dim3(256),         dim3(256), 0, stream>>>(z, A2);
  k_pass1   <<<dim3(NCH, 256),    dim3(256), 0, stream>>>(A2, B2, cand, cbc, rowMaxU);
  k_cstat2  <<<dim3(256),         dim3(256), 0, stream>>>(cand, cbc, rowMaxU, colsum,
                                                          ntList, ntc, scal);
  k_refine  <<<dim3(1024),        dim3(256), 0, stream>>>(z, emb, ntList, ntc, rowkey);
  k_zq      <<<dim3(256),         dim3(256), 0, stream>>>(A2, B2, rowkey, qids,
                                                          idxI, out + 4194308, out, scal);
  k_final   <<<dim3(1),           dim3(256), 0, stream>>>(idxI, qids, colsum, scal, out);
}

// Round 13
// 705.951 us; speedup vs baseline: 20.7870x; 1.0608x over previous
//
#include <hip/hip_runtime.h>
#include <math.h>

// Problem constants
#define N_TOK   16384
#define N_E     16384
#define CDIM    256
#define NCH     8
#define CHSZ    (N_E / NCH)      // 2048 codes per chunk
#define L2E100  144.26950408889634f   // 100 * log2(e)
#define DELTA_C 0.06f            // candidate window below running row max
#define EPS_NT  0.008f           // near-tie window for fp64 argmin re-rank
#define CAP_BLK 1536u            // per-block candidate cap (proven r6-r12)
#define NT_CAP  65536u

typedef __attribute__((ext_vector_type(8))) short short8;
typedef __attribute__((ext_vector_type(4))) float f32x4;

// ---- workspace layout (float offsets); base 42.5 MB, zT optional tail ----
#define OFF_A2   0u          // ushort[16384*256] bf16-hi normalized z (token-major)
#define OFF_B2   2097152u    // ushort[16384*256] bf16-hi normalized emb
#define OFF_RMX  4194304u    // 16384 u32 ordered-key row max
#define OFF_CS   4210688u    // 16384 colsum
#define OFF_SC   4227072u    // 16 scalars
#define OFF_RK   4227088u    // 16384 u64 rowkey (8B aligned)
#define OFF_NT   4259856u    // 65536 u32 near-tie list
#define OFF_NTC  4325392u    // 16
#define OFF_CBC  4325408u    // 2048 per-block counts
#define OFF_IDX  4327456u    // 16384 int
#define OFF_CAND 4343840u    // u64[2048*1536] {f32 t | row<<14|col} (8B aligned)
#define OFF_ZT   10635296u   // float[16384*256] raw z token-major (refine coalescing)
#define NEED_ZT_BYTES 59318400ull

__device__ __forceinline__ unsigned short f2bf(float x) {
  unsigned u = __float_as_uint(x);
  unsigned r = (u + 0x7fffu + ((u >> 16) & 1u)) >> 16;
  return (unsigned short)r;
}
__device__ __forceinline__ float bf2f(unsigned short h) {
  return __uint_as_float(((unsigned)h) << 16);
}
__device__ __forceinline__ unsigned fkey(float f) {      // order-preserving float->uint
  unsigned u = __float_as_uint(f);
  return (u & 0x80000000u) ? ~u : (u | 0x80000000u);
}
__device__ __forceinline__ float keyf(unsigned k) {
  return (k & 0x80000000u) ? __uint_as_float(k ^ 0x80000000u) : __uint_as_float(~k);
}

__device__ __forceinline__ void async_load16(const void* g, void* l) {
  __builtin_amdgcn_global_load_lds((const __attribute__((address_space(1))) void*)g,
                                   (__attribute__((address_space(3))) void*)l, 16, 0, 0);
}

__device__ __forceinline__ float blockReduceSum256(float v, float* sbuf) {
  __syncthreads();
  v += __shfl_down(v, 32);
  v += __shfl_down(v, 16);
  v += __shfl_down(v, 8);
  v += __shfl_down(v, 4);
  v += __shfl_down(v, 2);
  v += __shfl_down(v, 1);
  const int tid = threadIdx.x;
  if ((tid & 63) == 0) sbuf[tid >> 6] = v;
  __syncthreads();
  return sbuf[0] + sbuf[1] + sbuf[2] + sbuf[3];
}

// ---------- emb normalize (wave-per-row) + fused workspace zeroing ----------
__global__ __launch_bounds__(256) void k_norm_emb(const float* __restrict__ emb,
    unsigned short* __restrict__ B2, float* __restrict__ colsum,
    float* __restrict__ scalars, unsigned long long* __restrict__ rowkey,
    unsigned* __restrict__ ntc, unsigned* __restrict__ rowMaxU) {
  const int tid = threadIdx.x, lane = tid & 63, wv = tid >> 6;
  if (blockIdx.x < 64) {
    const int i = blockIdx.x * 256 + tid;
    colsum[i] = 0.f;
    rowkey[i] = ~0ull;
    rowMaxU[i] = 0u;
    if (i < 16) { scalars[i] = 0.f; ntc[i] = 0u; }
  }
  const int k = blockIdx.x * 4 + wv;
  const float4 v = *(const float4*)&emb[(size_t)k * CDIM + lane * 4];
  float ss = v.x * v.x + v.y * v.y + v.z * v.z + v.w * v.w;
#pragma unroll
  for (int off = 1; off < 64; off <<= 1) ss += __shfl_xor(ss, off);
  const float r = 1.0f / fmaxf(sqrtf(ss), 1e-12f);
  ushort4 o;
  o.x = f2bf(v.x * r); o.y = f2bf(v.y * r);
  o.z = f2bf(v.z * r); o.w = f2bf(v.w * r);
  *(ushort4*)&B2[(size_t)k * CDIM + lane * 4] = o;
}

// ---------- coalesced z normalize + optional raw token-major copy ----------
__global__ __launch_bounds__(256) void k_norm_z(const float* __restrict__ z,
                                                unsigned short* __restrict__ A2,
                                                float* __restrict__ zT) {
  __shared__ float ssb[4][64];
  __shared__ float rn[64];
  __shared__ unsigned short tile[64 * 264];
  __shared__ float tileF[64 * 260];
  const int b = blockIdx.x >> 4, hw0 = (blockIdx.x & 15) * 64;
  const int tid = threadIdx.x, cg = tid >> 6, hwl = tid & 63;
  float ss = 0.f;
#pragma unroll 8
  for (int i = 0; i < 64; ++i) {
    const int c = cg + i * 4;
    const float x = z[((size_t)(b * CDIM + c) << 10) + hw0 + hwl];
    ss = fmaf(x, x, ss);
  }
  ssb[cg][hwl] = ss;
  __syncthreads();
  if (tid < 64) {
    const float t = ssb[0][tid] + ssb[1][tid] + ssb[2][tid] + ssb[3][tid];
    rn[tid] = 1.0f / fmaxf(sqrtf(t), 1e-12f);
  }
  __syncthreads();
  const float r = rn[hwl];
#pragma unroll 8
  for (int i = 0; i < 64; ++i) {
    const int c = cg + i * 4;
    const float x = z[((size_t)(b * CDIM + c) << 10) + hw0 + hwl];
    tile[hwl * 264 + c] = f2bf(x * r);
    tileF[hwl * 260 + c] = x;
  }
  __syncthreads();
  const int rr = tid >> 5, tt = tid & 31;
#pragma unroll
  for (int it = 0; it < 8; ++it) {
    const int row = rr + 8 * it;
    const int token = b * 1024 + hw0 + row;
    const uint4 v = *(const uint4*)&tile[row * 264 + tt * 8];
    *(uint4*)&A2[(size_t)token * CDIM + tt * 8] = v;
    if (zT != nullptr) {
      const float4 f0 = *(const float4*)&tileF[row * 260 + tt * 4];
      const float4 f1 = *(const float4*)&tileF[row * 260 + 128 + tt * 4];
      *(float4*)&zT[(size_t)token * CDIM + tt * 4] = f0;
      *(float4*)&zT[(size_t)token * CDIM + 128 + tt * 4] = f1;
    }
  }
}

// ============ pass 1: A in REGISTERS (64 VGPR/lane), B dbuf as r8, t = 2*dot ============
__global__ __launch_bounds__(256, 2) void k_pass1(const unsigned short* __restrict__ A2,
    const unsigned short* __restrict__ B2,
    unsigned long long* __restrict__ cand, unsigned* __restrict__ cbc,
    unsigned* __restrict__ rowMaxU) {
  __shared__ alignas(16) unsigned short Bt[2][128 * 64];  // 2 x 16 KB B dbuf
  __shared__ unsigned smaxU[64];
  __shared__ unsigned lcnt;
  const int chunk = blockIdx.x, rt = blockIdx.y;
  const int r0 = rt * 64, k0 = chunk * CHSZ;
  const int blin = rt * NCH + chunk;
  const int tid = threadIdx.x, lane = tid & 63, w = tid >> 6;
  const int wrr = (w & 1) * 32, wc = (w >> 1) * 64;
  const int l15 = lane & 15, quad = lane >> 4;

  if (tid == 0) lcnt = 0u;
  if (tid < 64) smaxU[tid] = 0u;

  // A fragments -> registers (rows fixed per wave for whole kernel).
  // Layout matches MFMA A operand: row = wrr+ti*16+l15, k = st*64 + (kk*4+quad)*8.
  short8 afr[2][4][2];
#pragma unroll
  for (int ti = 0; ti < 2; ++ti) {
    const size_t rbase = (size_t)(r0 + wrr + ti * 16 + l15) * CDIM;
#pragma unroll
    for (int st = 0; st < 4; ++st)
#pragma unroll
      for (int kk = 0; kk < 2; ++kk)
        afr[ti][st][kk] = *(const short8*)&A2[rbase + st * 64 + (((kk << 2) | quad) * 8)];
  }

  // per-thread B staging bases (swizzle: position cg holds global group cg^(row&7))
  const unsigned short* bsrc[4];
  unsigned bdst[4];
#pragma unroll
  for (int i = 0; i < 4; ++i) {
    const int lin = i * 256 + tid;
    const int row = lin >> 3, cg = lin & 7;
    const int gcg = cg ^ (row & 7);
    bsrc[i] = B2 + (size_t)(k0 + row) * CDIM + gcg * 8;
    bdst[i] = (unsigned)lin * 16u;
  }
#pragma unroll
  for (int i = 0; i < 4; ++i)
    async_load16(bsrc[i], (char*)Bt[0] + bdst[i]);

  // hoisted B LDS read offsets
  int boff[4][2];
#pragma unroll
  for (int tj = 0; tj < 4; ++tj) {
    const int br = wc + tj * 16 + l15;
#pragma unroll
    for (int kk = 0; kk < 2; ++kk)
      boff[tj][kk] = br * 64 + ((((kk << 2) | quad) ^ (br & 7)) * 8);
  }
  __syncthreads();

  f32x4 acc[2][4];

  for (int ct = 0; ct < 16; ++ct) {
#pragma unroll
    for (int ti = 0; ti < 2; ++ti)
#pragma unroll
      for (int tj = 0; tj < 4; ++tj) acc[ti][tj] = (f32x4){0.f, 0.f, 0.f, 0.f};

#pragma unroll
    for (int st = 0; st < 4; ++st) {
      if (!(ct == 15 && st == 3)) {
        const int noff = (st < 3) ? (st + 1) * 64 : 32768;
        char* dbuf = (char*)Bt[(st + 1) & 1];
#pragma unroll
        for (int i = 0; i < 4; ++i)
          async_load16(bsrc[i] + noff, dbuf + bdst[i]);
      }
      const unsigned short* bp = Bt[st & 1];
#pragma unroll
      for (int kk = 0; kk < 2; ++kk) {
        short8 bfr[4];
#pragma unroll
        for (int tj = 0; tj < 4; ++tj)
          bfr[tj] = *(const short8*)&bp[boff[tj][kk]];
#pragma unroll
        for (int ti = 0; ti < 2; ++ti)
#pragma unroll
          for (int tj = 0; tj < 4; ++tj)
            acc[ti][tj] = __builtin_amdgcn_mfma_f32_16x16x32_bf16(afr[ti][st][kk], bfr[tj],
                                                                  acc[ti][tj], 0, 0, 0);
      }
      if (st == 3) {
        const int kb = k0 + ct * 128;
#pragma unroll
        for (int ti = 0; ti < 2; ++ti)
#pragma unroll
          for (int tj = 0; tj < 4; ++tj) {
            f32x4 a = acc[ti][tj];
#pragma unroll
            for (int r = 0; r < 4; ++r) a[r] = a[r] + a[r];   // t = 2*dot
            acc[ti][tj] = a;
          }
#pragma unroll
        for (int ti = 0; ti < 2; ++ti)
#pragma unroll
          for (int r = 0; r < 4; ++r) {
            float mt = fmaxf(fmaxf(acc[ti][0][r], acc[ti][1][r]),
                             fmaxf(acc[ti][2][r], acc[ti][3][r]));
            mt = fmaxf(mt, __shfl_xor(mt, 1));
            mt = fmaxf(mt, __shfl_xor(mt, 2));
            mt = fmaxf(mt, __shfl_xor(mt, 4));
            mt = fmaxf(mt, __shfl_xor(mt, 8));
            if (l15 == 0) atomicMax(&smaxU[wrr + ti * 16 + quad * 4 + r], fkey(mt));
          }
        __syncthreads();   // all waves' maxes visible -> tight threshold
#pragma unroll
        for (int ti = 0; ti < 2; ++ti)
#pragma unroll
          for (int r = 0; r < 4; ++r) {
            const int rowloc = wrr + ti * 16 + quad * 4 + r;
            const float thr = keyf(smaxU[rowloc]) - DELTA_C;
            const unsigned rowg = (unsigned)(r0 + rowloc);
#pragma unroll
            for (int tj = 0; tj < 4; ++tj) {
              const float t = acc[ti][tj][r];
              if (t >= thr) {
                const unsigned slot = atomicAdd(&lcnt, 1u);
                if (slot < CAP_BLK) {
                  const unsigned pr = (rowg << 14) | (unsigned)(kb + wc + tj * 16 + l15);
                  cand[(size_t)blin * CAP_BLK + slot] =
                      ((unsigned long long)__float_as_uint(t) << 32) | pr;
                }
              }
            }
          }
      }
      __syncthreads();
    }
#pragma unroll
    for (int i = 0; i < 4; ++i) bsrc[i] += 32768;
  }
  if (tid < 64) atomicMax(&rowMaxU[r0 + tid], smaxU[tid]);
  if (tid == 0) cbc[blin] = lcnt < CAP_BLK ? lcnt : CAP_BLK;
}

// ---------- fused candidate processing: block = rt, LDS-local Z/E ----------
__global__ __launch_bounds__(256) void k_cstat2(const unsigned long long* __restrict__ cand,
    const unsigned* __restrict__ cbc, const unsigned* __restrict__ rowMaxU,
    float* __restrict__ colsum, unsigned* __restrict__ ntList,
    unsigned* __restrict__ ntc, float* __restrict__ scalars) {
  __shared__ float lM[64], lZ[64], lE[64], lIZ[64];
  __shared__ float sbuf[4];
  const int rt = blockIdx.x, r0 = rt * 64;
  const int tid = threadIdx.x, lane = tid & 63;
  if (tid < 64) {
    lM[tid] = keyf(rowMaxU[r0 + tid]);
    lZ[tid] = 0.f; lE[tid] = 0.f;
  }
  __syncthreads();
  for (int sub = 0; sub < NCH; ++sub) {
    const int blin = rt * NCH + sub;
    const unsigned cnt = cbc[blin] < CAP_BLK ? cbc[blin] : CAP_BLK;
    for (unsigned i = tid; i < cnt; i += 256u) {
      const unsigned long long e = cand[(size_t)blin * CAP_BLK + i];
      const unsigned pr = (unsigned)(e & 0xFFFFFFFu);
      const float t = __uint_as_float((unsigned)(e >> 32));
      const int rowl = (int)((pr >> 14) & 63u);
      const float d = t - lM[rowl];
      const float ex = exp2f(d * L2E100);
      atomicAdd(&lZ[rowl], ex);
      atomicAdd(&lE[rowl], d * 100.0f * ex);
    }
  }
  __syncthreads();
  float ent = 0.f;
  if (tid < 64) {
    const float Z = lZ[tid];
    lIZ[tid] = 1.0f / Z;
    ent = logf(Z) - lE[tid] / Z;
  }
  const float es = blockReduceSum256(ent, sbuf);
  if (tid == 0) atomicAdd(&scalars[1], es);
  __syncthreads();
  for (int sub = 0; sub < NCH; ++sub) {
    const int blin = rt * NCH + sub;
    const unsigned cnt = cbc[blin] < CAP_BLK ? cbc[blin] : CAP_BLK;
    const unsigned lim = (cnt + 255u) & ~255u;
    for (unsigned i = tid; i < lim; i += 256u) {
      bool nt = false;
      unsigned pr = 0u;
      if (i < cnt) {
        const unsigned long long e = cand[(size_t)blin * CAP_BLK + i];
        pr = (unsigned)(e & 0xFFFFFFFu);
        const float t = __uint_as_float((unsigned)(e >> 32));
        const int rowl = (int)((pr >> 14) & 63u);
        const float d = t - lM[rowl];
        atomicAdd(&colsum[pr & 0x3FFFu], exp2f(d * L2E100) * lIZ[rowl]);
        nt = (d >= -EPS_NT);
      }
      const unsigned long long mask = __ballot(nt);
      const unsigned cw = (unsigned)__popcll(mask);
      unsigned base = 0u;
      if (lane == 0 && cw) base = atomicAdd(ntc, cw);
      base = __shfl((int)base, 0);
      if (nt) {
        const unsigned off = (unsigned)__popcll(mask & ((1ull << lane) - 1ull));
        const unsigned s = base + off;
        if (s < NT_CAP) ntList[s] = pr;
      }
    }
  }
}

// ---------- fp64 re-rank of near-tie candidates (coalesced zT if available) ----------
__global__ __launch_bounds__(256) void k_refine(const float* __restrict__ z,
    const float* __restrict__ zT, const float* __restrict__ emb,
    const unsigned* __restrict__ ntList, const unsigned* __restrict__ ntc,
    unsigned long long* __restrict__ rowkey) {
  const unsigned cnt = *ntc;
  const unsigned lim = cnt < NT_CAP ? cnt : NT_CAP;
  const int lane = threadIdx.x & 63, wv = threadIdx.x >> 6;
  for (unsigned slot = blockIdx.x * 4 + wv; slot < lim; slot += gridDim.x * 4) {
    const unsigned pr = ntList[slot];
    const int n = (int)(pr >> 14), k = (int)(pr & 0x3FFFu);
    const int b = n >> 10, hw = n & 1023;
    double sz = 0.0, se = 0.0, sp = 0.0;
#pragma unroll
    for (int u = 0; u < CDIM / 64; ++u) {
      const int c = lane + u * 64;
      const double zv = (zT != nullptr)
          ? (double)zT[(size_t)n * CDIM + c]
          : (double)z[((size_t)(b * CDIM + c) << 10) + hw];
      const double ev = (double)emb[(size_t)k * CDIM + c];
      sz = fma(zv, zv, sz); se = fma(ev, ev, se); sp = fma(zv, ev, sp);
    }
    for (int off = 32; off; off >>= 1) {
      sz += __shfl_down(sz, off);
      se += __shfl_down(se, off);
      sp += __shfl_down(sp, off);
    }
    if (lane == 0) {
      const double nz = fmax(sqrt(sz), 1e-12);
      const double ne = fmax(sqrt(se), 1e-12);
      const double d = sz / (nz * nz) + se / (ne * ne) - 2.0 * sp / (nz * ne);
      const unsigned long long key =
          (((unsigned long long)(d * 140737488355328.0)) << 14) | (unsigned long long)k;
      atomicMin(&rowkey[n], key);
    }
  }
}

// ---------- z_q gather + idx extraction + vq sums ----------
__global__ __launch_bounds__(256) void k_zq(const unsigned short* __restrict__ A2,
    const unsigned short* __restrict__ B2, const unsigned long long* __restrict__ rowkey,
    const long long* __restrict__ qids, int* __restrict__ idxI,
    float* __restrict__ outIdxF, float* __restrict__ outZ,
    float* __restrict__ scalars) {
  __shared__ int lidx[64];
  __shared__ unsigned short tile[64 * 264];
  __shared__ float sbuf[4];
  const int b = blockIdx.x >> 4, hw0 = (blockIdx.x & 15) * 64;
  const int tid = threadIdx.x;
  if (tid < 64) {
    const int n = b * 1024 + hw0 + tid;
    const unsigned long long key = rowkey[n];
    const int k = (key != ~0ull) ? (int)(key & 0x3FFFull) : 0;
    lidx[tid] = k;
    idxI[n] = k;
    outIdxF[n] = (float)k;
  }
  __syncthreads();
  const long long qid = qids[b];
  const int rr = tid >> 5, tt = tid & 31;
  float vq = 0.f;
#pragma unroll
  for (int it = 0; it < 8; ++it) {
    const int row = rr + 8 * it;
    const int token = b * 1024 + hw0 + row;
    union { uint4 v; unsigned short s[8]; } ev, zv;
    ev.v = *(const uint4*)&B2[(size_t)lidx[row] * CDIM + tt * 8];
    zv.v = *(const uint4*)&A2[(size_t)token * CDIM + tt * 8];
    *(uint4*)&tile[row * 264 + tt * 8] = ev.v;
    float dd = 0.f;
#pragma unroll
    for (int u = 0; u < 8; ++u) {
      const float d = bf2f(ev.s[u]) - bf2f(zv.s[u]);
      dd = fmaf(d, d, dd);
    }
    if ((long long)(row & 31) <= qid) vq += dd;
  }
  const float s = blockReduceSum256(vq, sbuf);
  if (tid == 0) atomicAdd(&scalars[0], s * (1.0f / 256.0f));
  __syncthreads();
  const int cg = tid >> 6, hwl = tid & 63;
#pragma unroll 8
  for (int i = 0; i < 64; ++i) {
    const int c = cg + i * 4;
    outZ[((size_t)(b * CDIM + c) << 10) + hw0 + hwl] = bf2f(tile[hwl * 264 + c]);
  }
}

// ---------- final: avg-entropy from colsum + dead-code + scalar outputs ----------
__global__ __launch_bounds__(256) void k_final(const int* __restrict__ idxI,
    const long long* __restrict__ qids, const float* __restrict__ colsum,
    const float* __restrict__ scalars, float* __restrict__ out) {
  __shared__ float sbuf[4];
  const int tid = threadIdx.x;
  float ae = 0.f;
  for (int i = tid; i < N_E; i += 256) {
    const float q = colsum[i] * (1.0f / (float)N_TOK);
    ae += q * logf(q + 1e-5f);
  }
  const float aes = blockReduceSum256(ae, sbuf);   // = -avg_entropy
  int cnt = 0;
  for (int p = tid; p < 1024; p += 256) {
    const int v = idxI[p];
    bool eq = true;
    for (int b = 1; b < 16; ++b) eq = eq && (idxI[b * 1024 + p] == v);
    cnt += eq ? 1 : 0;
  }
  const float dc = blockReduceSum256((float)cnt, sbuf);
  if (tid == 0) {
    float denom = 0.f;
    for (int b = 0; b < 16; ++b) denom += (float)(qids[b] + 1ll);
    out[4194304] = scalars[0] / denom;
    out[4194305] = 0.25f * scalars[0] / denom;
    out[4194306] = 0.1f * (scalars[1] * (1.0f / (float)N_TOK) + aes);
    out[4194307] = dc * (1.0f / 1024.0f);
  }
}

extern "C" void kernel_launch(void* const* d_in, const int* in_sizes, int n_in,
                              void* d_out, int out_size, void* d_ws, size_t ws_size,
                              hipStream_t stream) {
  const float*      z    = (const float*)d_in[0];
  const float*      emb  = (const float*)d_in[1];
  const long long*  qids = (const long long*)d_in[2];
  float* out = (float*)d_out;
  float* W   = (float*)d_ws;

  unsigned short* A2 = (unsigned short*)(W + OFF_A2);
  unsigned short* B2 = (unsigned short*)(W + OFF_B2);
  unsigned* rowMaxU = (unsigned*)(W + OFF_RMX);
  float* colsum = W + OFF_CS;
  float* scal   = W + OFF_SC;
  unsigned long long* rowkey = (unsigned long long*)(W + OFF_RK);
  unsigned* ntList = (unsigned*)(W + OFF_NT);
  unsigned* ntc    = (unsigned*)(W + OFF_NTC);
  unsigned* cbc    = (unsigned*)(W + OFF_CBC);
  int* idxI        = (int*)(W + OFF_IDX);
  unsigned long long* cand = (unsigned long long*)(W + OFF_CAND);
  float* zT = (ws_size >= NEED_ZT_BYTES) ? (W + OFF_ZT) : (float*)nullptr;

  k_norm_emb<<<dim3(N_E / 4),     dim3(256), 0, stream>>>(emb, B2, colsum, scal,
                                                          rowkey, ntc, rowMaxU);
  k_norm_z  <<<dim3(256),         dim3(256), 0, stream>>>(z, A2, zT);
  k_pass1   <<<dim3(NCH, 256),    dim3(256), 0, stream>>>(A2, B2, cand, cbc, rowMaxU);
  k_cstat2  <<<dim3(256),         dim3(256), 0, stream>>>(cand, cbc, rowMaxU, colsum,
                                                          ntList, ntc, scal);
  k_refine  <<<dim3(1024),        dim3(256), 0, stream>>>(z, zT, emb, ntList, ntc, rowkey);
  k_zq      <<<dim3(256),         dim3(256), 0, stream>>>(A2, B2, rowkey, qids,
                                                          idxI, out + 4194308, out, scal);
  k_final   <<<dim3(1),           dim3(256), 0, stream>>>(idxI, qids, colsum, scal, out);
}

// Round 14
// 687.631 us; speedup vs baseline: 21.3408x; 1.0266x over previous
//
#include <hip/hip_runtime.h>
#include <math.h>

// Problem constants
#define N_TOK   16384
#define N_E     16384
#define CDIM    256
#define NCH     8
#define CHSZ    (N_E / NCH)      // 2048 codes per chunk
#define L2E100  144.26950408889634f   // 100 * log2(e)
#define DELTA_C 0.06f            // candidate window below running row max
#define EPS_NT  0.008f           // near-tie window for fp64 argmin re-rank
#define CAP_BLK 1536u            // per-block candidate cap (proven r6-r13)
#define NT_CAP  65536u

typedef __attribute__((ext_vector_type(8))) short short8;
typedef __attribute__((ext_vector_type(4))) float f32x4;

// ---- workspace layout (float offsets); base 42.5 MB, zT optional tail ----
#define OFF_A2   0u          // ushort[16384*256] bf16-hi normalized z (token-major)
#define OFF_B2   2097152u    // ushort[16384*256] bf16-hi normalized emb
#define OFF_RMX  4194304u    // 16384 u32 ordered-key row max
#define OFF_CS   4210688u    // 16384 colsum
#define OFF_SC   4227072u    // 16 scalars
#define OFF_RK   4227088u    // 16384 u64 rowkey (8B aligned)
#define OFF_NT   4259856u    // 65536 u32 near-tie list
#define OFF_NTC  4325392u    // 16
#define OFF_CBC  4325408u    // 2048 per-block counts
#define OFF_IDX  4327456u    // 16384 int
#define OFF_CAND 4343840u    // u64[2048*1536] {f32 t | row<<14|col} (8B aligned)
#define OFF_ZT   10635296u   // float[16384*256] raw z token-major (refine coalescing)
#define NEED_ZT_BYTES 59318400ull

__device__ __forceinline__ unsigned short f2bf(float x) {
  unsigned u = __float_as_uint(x);
  unsigned r = (u + 0x7fffu + ((u >> 16) & 1u)) >> 16;
  return (unsigned short)r;
}
__device__ __forceinline__ float bf2f(unsigned short h) {
  return __uint_as_float(((unsigned)h) << 16);
}
__device__ __forceinline__ unsigned fkey(float f) {      // order-preserving float->uint
  unsigned u = __float_as_uint(f);
  return (u & 0x80000000u) ? ~u : (u | 0x80000000u);
}
__device__ __forceinline__ float keyf(unsigned k) {
  return (k & 0x80000000u) ? __uint_as_float(k ^ 0x80000000u) : __uint_as_float(~k);
}

__device__ __forceinline__ void async_load16(const void* g, void* l) {
  __builtin_amdgcn_global_load_lds((const __attribute__((address_space(1))) void*)g,
                                   (__attribute__((address_space(3))) void*)l, 16, 0, 0);
}

__device__ __forceinline__ float blockReduceSum256(float v, float* sbuf) {
  __syncthreads();
  v += __shfl_down(v, 32);
  v += __shfl_down(v, 16);
  v += __shfl_down(v, 8);
  v += __shfl_down(v, 4);
  v += __shfl_down(v, 2);
  v += __shfl_down(v, 1);
  const int tid = threadIdx.x;
  if ((tid & 63) == 0) sbuf[tid >> 6] = v;
  __syncthreads();
  return sbuf[0] + sbuf[1] + sbuf[2] + sbuf[3];
}

// ---------- emb normalize (wave-per-row) + fused workspace zeroing ----------
__global__ __launch_bounds__(256) void k_norm_emb(const float* __restrict__ emb,
    unsigned short* __restrict__ B2, float* __restrict__ colsum,
    float* __restrict__ scalars, unsigned long long* __restrict__ rowkey,
    unsigned* __restrict__ ntc, unsigned* __restrict__ rowMaxU) {
  const int tid = threadIdx.x, lane = tid & 63, wv = tid >> 6;
  if (blockIdx.x < 64) {
    const int i = blockIdx.x * 256 + tid;
    colsum[i] = 0.f;
    rowkey[i] = ~0ull;
    rowMaxU[i] = 0u;
    if (i < 16) { scalars[i] = 0.f; ntc[i] = 0u; }
  }
  const int k = blockIdx.x * 4 + wv;
  const float4 v = *(const float4*)&emb[(size_t)k * CDIM + lane * 4];
  float ss = v.x * v.x + v.y * v.y + v.z * v.z + v.w * v.w;
#pragma unroll
  for (int off = 1; off < 64; off <<= 1) ss += __shfl_xor(ss, off);
  const float r = 1.0f / fmaxf(sqrtf(ss), 1e-12f);
  ushort4 o;
  o.x = f2bf(v.x * r); o.y = f2bf(v.y * r);
  o.z = f2bf(v.z * r); o.w = f2bf(v.w * r);
  *(ushort4*)&B2[(size_t)k * CDIM + lane * 4] = o;
}

// ---------- coalesced z normalize + optional raw token-major copy ----------
__global__ __launch_bounds__(256) void k_norm_z(const float* __restrict__ z,
                                                unsigned short* __restrict__ A2,
                                                float* __restrict__ zT) {
  __shared__ float ssb[4][64];
  __shared__ float rn[64];
  __shared__ unsigned short tile[64 * 264];
  __shared__ float tileF[64 * 260];
  const int b = blockIdx.x >> 4, hw0 = (blockIdx.x & 15) * 64;
  const int tid = threadIdx.x, cg = tid >> 6, hwl = tid & 63;
  float ss = 0.f;
#pragma unroll 8
  for (int i = 0; i < 64; ++i) {
    const int c = cg + i * 4;
    const float x = z[((size_t)(b * CDIM + c) << 10) + hw0 + hwl];
    ss = fmaf(x, x, ss);
  }
  ssb[cg][hwl] = ss;
  __syncthreads();
  if (tid < 64) {
    const float t = ssb[0][tid] + ssb[1][tid] + ssb[2][tid] + ssb[3][tid];
    rn[tid] = 1.0f / fmaxf(sqrtf(t), 1e-12f);
  }
  __syncthreads();
  const float r = rn[hwl];
#pragma unroll 8
  for (int i = 0; i < 64; ++i) {
    const int c = cg + i * 4;
    const float x = z[((size_t)(b * CDIM + c) << 10) + hw0 + hwl];
    tile[hwl * 264 + c] = f2bf(x * r);
    tileF[hwl * 260 + c] = x;
  }
  __syncthreads();
  const int rr = tid >> 5, tt = tid & 31;
#pragma unroll
  for (int it = 0; it < 8; ++it) {
    const int row = rr + 8 * it;
    const int token = b * 1024 + hw0 + row;
    const uint4 v = *(const uint4*)&tile[row * 264 + tt * 8];
    *(uint4*)&A2[(size_t)token * CDIM + tt * 8] = v;
    if (zT != nullptr) {
      const float4 f0 = *(const float4*)&tileF[row * 260 + tt * 4];
      const float4 f1 = *(const float4*)&tileF[row * 260 + 128 + tt * 4];
      *(float4*)&zT[(size_t)token * CDIM + tt * 4] = f0;
      *(float4*)&zT[(size_t)token * CDIM + 128 + tt * 4] = f1;
    }
  }
}

// ============ pass 1: A in registers, B dbuf, 4 blocks/CU, t = 2*dot ============
__global__ __launch_bounds__(256, 4) void k_pass1(const unsigned short* __restrict__ A2,
    const unsigned short* __restrict__ B2,
    unsigned long long* __restrict__ cand, unsigned* __restrict__ cbc,
    unsigned* __restrict__ rowMaxU) {
  __shared__ alignas(16) unsigned short Bt[2][128 * 64];  // 2 x 16 KB B dbuf
  __shared__ unsigned smaxU[64];
  __shared__ unsigned lcnt;
  const int rt = blockIdx.x, chunk = blockIdx.y;   // swizzle: co-resident blocks share chunk
  const int r0 = rt * 64, k0 = chunk * CHSZ;
  const int blin = rt * NCH + chunk;
  const int tid = threadIdx.x, lane = tid & 63, w = tid >> 6;
  const int wrr = (w & 1) * 32, wc = (w >> 1) * 64;
  const int l15 = lane & 15, quad = lane >> 4;

  if (tid == 0) lcnt = 0u;
  if (tid < 64) smaxU[tid] = 0u;

  // A fragments -> registers (rows fixed per wave for whole kernel).
  short8 afr[2][4][2];
#pragma unroll
  for (int ti = 0; ti < 2; ++ti) {
    const size_t rbase = (size_t)(r0 + wrr + ti * 16 + l15) * CDIM;
#pragma unroll
    for (int st = 0; st < 4; ++st)
#pragma unroll
      for (int kk = 0; kk < 2; ++kk)
        afr[ti][st][kk] = *(const short8*)&A2[rbase + st * 64 + (((kk << 2) | quad) * 8)];
  }

  // per-thread B staging bases (swizzle: position cg holds global group cg^(row&7))
  const unsigned short* bsrc[4];
  unsigned bdst[4];
#pragma unroll
  for (int i = 0; i < 4; ++i) {
    const int lin = i * 256 + tid;
    const int row = lin >> 3, cg = lin & 7;
    const int gcg = cg ^ (row & 7);
    bsrc[i] = B2 + (size_t)(k0 + row) * CDIM + gcg * 8;
    bdst[i] = (unsigned)lin * 16u;
  }
#pragma unroll
  for (int i = 0; i < 4; ++i)
    async_load16(bsrc[i], (char*)Bt[0] + bdst[i]);

  // hoisted B LDS read offsets
  int boff[4][2];
#pragma unroll
  for (int tj = 0; tj < 4; ++tj) {
    const int br = wc + tj * 16 + l15;
#pragma unroll
    for (int kk = 0; kk < 2; ++kk)
      boff[tj][kk] = br * 64 + ((((kk << 2) | quad) ^ (br & 7)) * 8);
  }
  __syncthreads();

  f32x4 acc[2][4];

  for (int ct = 0; ct < 16; ++ct) {
#pragma unroll
    for (int ti = 0; ti < 2; ++ti)
#pragma unroll
      for (int tj = 0; tj < 4; ++tj) acc[ti][tj] = (f32x4){0.f, 0.f, 0.f, 0.f};

#pragma unroll
    for (int st = 0; st < 4; ++st) {
      if (!(ct == 15 && st == 3)) {
        const int noff = (st < 3) ? (st + 1) * 64 : 32768;
        char* dbuf = (char*)Bt[(st + 1) & 1];
#pragma unroll
        for (int i = 0; i < 4; ++i)
          async_load16(bsrc[i] + noff, dbuf + bdst[i]);
      }
      const unsigned short* bp = Bt[st & 1];
#pragma unroll
      for (int kk = 0; kk < 2; ++kk) {
        short8 bfr[4];
#pragma unroll
        for (int tj = 0; tj < 4; ++tj)
          bfr[tj] = *(const short8*)&bp[boff[tj][kk]];
#pragma unroll
        for (int ti = 0; ti < 2; ++ti)
#pragma unroll
          for (int tj = 0; tj < 4; ++tj)
            acc[ti][tj] = __builtin_amdgcn_mfma_f32_16x16x32_bf16(afr[ti][st][kk], bfr[tj],
                                                                  acc[ti][tj], 0, 0, 0);
      }
      if (st == 3) {
        const int kb = k0 + ct * 128;
#pragma unroll
        for (int ti = 0; ti < 2; ++ti)
#pragma unroll
          for (int tj = 0; tj < 4; ++tj) {
            f32x4 a = acc[ti][tj];
#pragma unroll
            for (int r = 0; r < 4; ++r) a[r] = a[r] + a[r];   // t = 2*dot
            acc[ti][tj] = a;
          }
#pragma unroll
        for (int ti = 0; ti < 2; ++ti)
#pragma unroll
          for (int r = 0; r < 4; ++r) {
            float mt = fmaxf(fmaxf(acc[ti][0][r], acc[ti][1][r]),
                             fmaxf(acc[ti][2][r], acc[ti][3][r]));
            mt = fmaxf(mt, __shfl_xor(mt, 1));
            mt = fmaxf(mt, __shfl_xor(mt, 2));
            mt = fmaxf(mt, __shfl_xor(mt, 4));
            mt = fmaxf(mt, __shfl_xor(mt, 8));
            if (l15 == 0) atomicMax(&smaxU[wrr + ti * 16 + quad * 4 + r], fkey(mt));
          }
        __syncthreads();   // all waves' maxes visible -> tight threshold
#pragma unroll
        for (int ti = 0; ti < 2; ++ti)
#pragma unroll
          for (int r = 0; r < 4; ++r) {
            const int rowloc = wrr + ti * 16 + quad * 4 + r;
            const float thr = keyf(smaxU[rowloc]) - DELTA_C;
            const unsigned rowg = (unsigned)(r0 + rowloc);
#pragma unroll
            for (int tj = 0; tj < 4; ++tj) {
              const float t = acc[ti][tj][r];
              if (t >= thr) {
                const unsigned slot = atomicAdd(&lcnt, 1u);
                if (slot < CAP_BLK) {
                  const unsigned pr = (rowg << 14) | (unsigned)(kb + wc + tj * 16 + l15);
                  cand[(size_t)blin * CAP_BLK + slot] =
                      ((unsigned long long)__float_as_uint(t) << 32) | pr;
                }
              }
            }
          }
      }
      __syncthreads();
    }
#pragma unroll
    for (int i = 0; i < 4; ++i) bsrc[i] += 32768;
  }
  if (tid < 64) atomicMax(&rowMaxU[r0 + tid], smaxU[tid]);
  if (tid == 0) cbc[blin] = lcnt < CAP_BLK ? lcnt : CAP_BLK;
}

// ---------- fused candidate processing: block = rt, LDS-local Z/E ----------
__global__ __launch_bounds__(256) void k_cstat2(const unsigned long long* __restrict__ cand,
    const unsigned* __restrict__ cbc, const unsigned* __restrict__ rowMaxU,
    float* __restrict__ colsum, unsigned* __restrict__ ntList,
    unsigned* __restrict__ ntc, float* __restrict__ scalars) {
  __shared__ float lM[64], lZ[64], lE[64], lIZ[64];
  __shared__ float sbuf[4];
  const int rt = blockIdx.x, r0 = rt * 64;
  const int tid = threadIdx.x, lane = tid & 63;
  if (tid < 64) {
    lM[tid] = keyf(rowMaxU[r0 + tid]);
    lZ[tid] = 0.f; lE[tid] = 0.f;
  }
  __syncthreads();
  for (int sub = 0; sub < NCH; ++sub) {
    const int blin = rt * NCH + sub;
    const unsigned cnt = cbc[blin] < CAP_BLK ? cbc[blin] : CAP_BLK;
    for (unsigned i = tid; i < cnt; i += 256u) {
      const unsigned long long e = cand[(size_t)blin * CAP_BLK + i];
      const unsigned pr = (unsigned)(e & 0xFFFFFFFu);
      const float t = __uint_as_float((unsigned)(e >> 32));
      const int rowl = (int)((pr >> 14) & 63u);
      const float d = t - lM[rowl];
      const float ex = exp2f(d * L2E100);
      atomicAdd(&lZ[rowl], ex);
      atomicAdd(&lE[rowl], d * 100.0f * ex);
    }
  }
  __syncthreads();
  float ent = 0.f;
  if (tid < 64) {
    const float Z = lZ[tid];
    lIZ[tid] = 1.0f / Z;
    ent = logf(Z) - lE[tid] / Z;
  }
  const float es = blockReduceSum256(ent, sbuf);
  if (tid == 0) atomicAdd(&scalars[1], es);
  __syncthreads();
  for (int sub = 0; sub < NCH; ++sub) {
    const int blin = rt * NCH + sub;
    const unsigned cnt = cbc[blin] < CAP_BLK ? cbc[blin] : CAP_BLK;
    const unsigned lim = (cnt + 255u) & ~255u;
    for (unsigned i = tid; i < lim; i += 256u) {
      bool nt = false;
      unsigned pr = 0u;
      if (i < cnt) {
        const unsigned long long e = cand[(size_t)blin * CAP_BLK + i];
        pr = (unsigned)(e & 0xFFFFFFFu);
        const float t = __uint_as_float((unsigned)(e >> 32));
        const int rowl = (int)((pr >> 14) & 63u);
        const float d = t - lM[rowl];
        atomicAdd(&colsum[pr & 0x3FFFu], exp2f(d * L2E100) * lIZ[rowl]);
        nt = (d >= -EPS_NT);
      }
      const unsigned long long mask = __ballot(nt);
      const unsigned cw = (unsigned)__popcll(mask);
      unsigned base = 0u;
      if (lane == 0 && cw) base = atomicAdd(ntc, cw);
      base = __shfl((int)base, 0);
      if (nt) {
        const unsigned off = (unsigned)__popcll(mask & ((1ull << lane) - 1ull));
        const unsigned s = base + off;
        if (s < NT_CAP) ntList[s] = pr;
      }
    }
  }
}

// ---------- fp64 re-rank of near-tie candidates (coalesced zT if available) ----------
__global__ __launch_bounds__(256) void k_refine(const float* __restrict__ z,
    const float* __restrict__ zT, const float* __restrict__ emb,
    const unsigned* __restrict__ ntList, const unsigned* __restrict__ ntc,
    unsigned long long* __restrict__ rowkey) {
  const unsigned cnt = *ntc;
  const unsigned lim = cnt < NT_CAP ? cnt : NT_CAP;
  const int lane = threadIdx.x & 63, wv = threadIdx.x >> 6;
  for (unsigned slot = blockIdx.x * 4 + wv; slot < lim; slot += gridDim.x * 4) {
    const unsigned pr = ntList[slot];
    const int n = (int)(pr >> 14), k = (int)(pr & 0x3FFFu);
    const int b = n >> 10, hw = n & 1023;
    double sz = 0.0, se = 0.0, sp = 0.0;
#pragma unroll
    for (int u = 0; u < CDIM / 64; ++u) {
      const int c = lane + u * 64;
      const double zv = (zT != nullptr)
          ? (double)zT[(size_t)n * CDIM + c]
          : (double)z[((size_t)(b * CDIM + c) << 10) + hw];
      const double ev = (double)emb[(size_t)k * CDIM + c];
      sz = fma(zv, zv, sz); se = fma(ev, ev, se); sp = fma(zv, ev, sp);
    }
    for (int off = 32; off; off >>= 1) {
      sz += __shfl_down(sz, off);
      se += __shfl_down(se, off);
      sp += __shfl_down(sp, off);
    }
    if (lane == 0) {
      const double nz = fmax(sqrt(sz), 1e-12);
      const double ne = fmax(sqrt(se), 1e-12);
      const double d = sz / (nz * nz) + se / (ne * ne) - 2.0 * sp / (nz * ne);
      const unsigned long long key =
          (((unsigned long long)(d * 140737488355328.0)) << 14) | (unsigned long long)k;
      atomicMin(&rowkey[n], key);
    }
  }
}

// ---------- z_q gather + idx extraction + vq sums ----------
__global__ __launch_bounds__(256) void k_zq(const unsigned short* __restrict__ A2,
    const unsigned short* __restrict__ B2, const unsigned long long* __restrict__ rowkey,
    const long long* __restrict__ qids, int* __restrict__ idxI,
    float* __restrict__ outIdxF, float* __restrict__ outZ,
    float* __restrict__ scalars) {
  __shared__ int lidx[64];
  __shared__ unsigned short tile[64 * 264];
  __shared__ float sbuf[4];
  const int b = blockIdx.x >> 4, hw0 = (blockIdx.x & 15) * 64;
  const int tid = threadIdx.x;
  if (tid < 64) {
    const int n = b * 1024 + hw0 + tid;
    const unsigned long long key = rowkey[n];
    const int k = (key != ~0ull) ? (int)(key & 0x3FFFull) : 0;
    lidx[tid] = k;
    idxI[n] = k;
    outIdxF[n] = (float)k;
  }
  __syncthreads();
  const long long qid = qids[b];
  const int rr = tid >> 5, tt = tid & 31;
  float vq = 0.f;
#pragma unroll
  for (int it = 0; it < 8; ++it) {
    const int row = rr + 8 * it;
    const int token = b * 1024 + hw0 + row;
    union { uint4 v; unsigned short s[8]; } ev, zv;
    ev.v = *(const uint4*)&B2[(size_t)lidx[row] * CDIM + tt * 8];
    zv.v = *(const uint4*)&A2[(size_t)token * CDIM + tt * 8];
    *(uint4*)&tile[row * 264 + tt * 8] = ev.v;
    float dd = 0.f;
#pragma unroll
    for (int u = 0; u < 8; ++u) {
      const float d = bf2f(ev.s[u]) - bf2f(zv.s[u]);
      dd = fmaf(d, d, dd);
    }
    if ((long long)(row & 31) <= qid) vq += dd;
  }
  const float s = blockReduceSum256(vq, sbuf);
  if (tid == 0) atomicAdd(&scalars[0], s * (1.0f / 256.0f));
  __syncthreads();
  const int cg = tid >> 6, hwl = tid & 63;
#pragma unroll 8
  for (int i = 0; i < 64; ++i) {
    const int c = cg + i * 4;
    outZ[((size_t)(b * CDIM + c) << 10) + hw0 + hwl] = bf2f(tile[hwl * 264 + c]);
  }
}

// ---------- final: avg-entropy from colsum + dead-code + scalar outputs ----------
__global__ __launch_bounds__(256) void k_final(const int* __restrict__ idxI,
    const long long* __restrict__ qids, const float* __restrict__ colsum,
    const float* __restrict__ scalars, float* __restrict__ out) {
  __shared__ float sbuf[4];
  const int tid = threadIdx.x;
  float ae = 0.f;
  for (int i = tid; i < N_E; i += 256) {
    const float q = colsum[i] * (1.0f / (float)N_TOK);
    ae += q * logf(q + 1e-5f);
  }
  const float aes = blockReduceSum256(ae, sbuf);   // = -avg_entropy
  int cnt = 0;
  for (int p = tid; p < 1024; p += 256) {
    const int v = idxI[p];
    bool eq = true;
    for (int b = 1; b < 16; ++b) eq = eq && (idxI[b * 1024 + p] == v);
    cnt += eq ? 1 : 0;
  }
  const float dc = blockReduceSum256((float)cnt, sbuf);
  if (tid == 0) {
    float denom = 0.f;
    for (int b = 0; b < 16; ++b) denom += (float)(qids[b] + 1ll);
    out[4194304] = scalars[0] / denom;
    out[4194305] = 0.25f * scalars[0] / denom;
    out[4194306] = 0.1f * (scalars[1] * (1.0f / (float)N_TOK) + aes);
    out[4194307] = dc * (1.0f / 1024.0f);
  }
}

extern "C" void kernel_launch(void* const* d_in, const int* in_sizes, int n_in,
                              void* d_out, int out_size, void* d_ws, size_t ws_size,
                              hipStream_t stream) {
  const float*      z    = (const float*)d_in[0];
  const float*      emb  = (const float*)d_in[1];
  const long long*  qids = (const long long*)d_in[2];
  float* out = (float*)d_out;
  float* W   = (float*)d_ws;

  unsigned short* A2 = (unsigned short*)(W + OFF_A2);
  unsigned short* B2 = (unsigned short*)(W + OFF_B2);
  unsigned* rowMaxU = (unsigned*)(W + OFF_RMX);
  float* colsum = W + OFF_CS;
  float* scal   = W + OFF_SC;
  unsigned long long* rowkey = (unsigned long long*)(W + OFF_RK);
  unsigned* ntList = (unsigned*)(W + OFF_NT);
  unsigned* ntc    = (unsigned*)(W + OFF_NTC);
  unsigned* cbc    = (unsigned*)(W + OFF_CBC);
  int* idxI        = (int*)(W + OFF_IDX);
  unsigned long long* cand = (unsigned long long*)(W + OFF_CAND);
  float* zT = (ws_size >= NEED_ZT_BYTES) ? (W + OFF_ZT) : (float*)nullptr;

  k_norm_emb<<<dim3(N_E / 4),     dim3(256), 0, stream>>>(emb, B2, colsum, scal,
                                                          rowkey, ntc, rowMaxU);
  k_norm_z  <<<dim3(256),         dim3(256), 0, stream>>>(z, A2, zT);
  k_pass1   <<<dim3(256, NCH),    dim3(256), 0, stream>>>(A2, B2, cand, cbc, rowMaxU);
  k_cstat2  <<<dim3(256),         dim3(256), 0, stream>>>(cand, cbc, rowMaxU, colsum,
                                                          ntList, ntc, scal);
  k_refine  <<<dim3(1024),        dim3(256), 0, stream>>>(z, zT, emb, ntList, ntc, rowkey);
  k_zq      <<<dim3(256),         dim3(256), 0, stream>>>(A2, B2, rowkey, qids,
                                                          idxI, out + 4194308, out, scal);
  k_final   <<<dim3(1),           dim3(256), 0, stream>>>(idxI, qids, colsum, scal, out);
}

// Round 15
// 645.046 us; speedup vs baseline: 22.7497x; 1.0660x over previous
//
#include <hip/hip_runtime.h>
#include <math.h>

// Problem constants
#define N_TOK   16384
#define N_E     16384
#define CDIM    256
#define NCH     8
#define CHSZ    (N_E / NCH)      // 2048 codes per chunk
#define L2E100  144.26950408889634f   // 100 * log2(e)
#define DELTA_C 0.06f            // candidate window below running row max
#define EPS_NT  0.008f           // near-tie window for fp64 argmin re-rank
#define CAP_BLK 1536u            // per-block candidate cap (proven r6-r14)
#define NT_CAP  65536u

typedef __attribute__((ext_vector_type(8))) short short8;
typedef __attribute__((ext_vector_type(4))) float f32x4;

// ---- workspace layout (float offsets); base 42.5 MB, zT optional tail ----
#define OFF_A2   0u          // ushort[16384*256] bf16-hi normalized z (token-major)
#define OFF_B2   2097152u    // ushort[16384*256] bf16-hi normalized emb
#define OFF_RMX  4194304u    // 16384 u32 ordered-key row max
#define OFF_CS   4210688u    // 16384 colsum
#define OFF_SC   4227072u    // 16 scalars
#define OFF_RK   4227088u    // 16384 u64 rowkey (8B aligned)
#define OFF_NT   4259856u    // 65536 u32 near-tie list
#define OFF_NTC  4325392u    // 16
#define OFF_CBC  4325408u    // 2048 per-block counts
#define OFF_IDX  4327456u    // 16384 int
#define OFF_CAND 4343840u    // u64[2048*1536] {f32 t | row<<14|col} (8B aligned)
#define OFF_ZT   10635296u   // float[16384*256] raw z token-major (refine coalescing)
#define NEED_ZT_BYTES 59318400ull

__device__ __forceinline__ unsigned short f2bf(float x) {
  unsigned u = __float_as_uint(x);
  unsigned r = (u + 0x7fffu + ((u >> 16) & 1u)) >> 16;
  return (unsigned short)r;
}
__device__ __forceinline__ float bf2f(unsigned short h) {
  return __uint_as_float(((unsigned)h) << 16);
}
__device__ __forceinline__ unsigned fkey(float f) {      // order-preserving float->uint
  unsigned u = __float_as_uint(f);
  return (u & 0x80000000u) ? ~u : (u | 0x80000000u);
}
__device__ __forceinline__ float keyf(unsigned k) {
  return (k & 0x80000000u) ? __uint_as_float(k ^ 0x80000000u) : __uint_as_float(~k);
}

__device__ __forceinline__ void async_load16(const void* g, void* l) {
  __builtin_amdgcn_global_load_lds((const __attribute__((address_space(1))) void*)g,
                                   (__attribute__((address_space(3))) void*)l, 16, 0, 0);
}

__device__ __forceinline__ float blockReduceSum256(float v, float* sbuf) {
  __syncthreads();
  v += __shfl_down(v, 32);
  v += __shfl_down(v, 16);
  v += __shfl_down(v, 8);
  v += __shfl_down(v, 4);
  v += __shfl_down(v, 2);
  v += __shfl_down(v, 1);
  const int tid = threadIdx.x;
  if ((tid & 63) == 0) sbuf[tid >> 6] = v;
  __syncthreads();
  return sbuf[0] + sbuf[1] + sbuf[2] + sbuf[3];
}

// ---------- emb normalize (wave-per-row) + fused workspace zeroing ----------
__global__ __launch_bounds__(256) void k_norm_emb(const float* __restrict__ emb,
    unsigned short* __restrict__ B2, float* __restrict__ colsum,
    float* __restrict__ scalars, unsigned long long* __restrict__ rowkey,
    unsigned* __restrict__ ntc, unsigned* __restrict__ rowMaxU) {
  const int tid = threadIdx.x, lane = tid & 63, wv = tid >> 6;
  if (blockIdx.x < 64) {
    const int i = blockIdx.x * 256 + tid;
    colsum[i] = 0.f;
    rowkey[i] = ~0ull;
    rowMaxU[i] = 0u;
    if (i < 16) { scalars[i] = 0.f; ntc[i] = 0u; }
  }
  const int k = blockIdx.x * 4 + wv;
  const float4 v = *(const float4*)&emb[(size_t)k * CDIM + lane * 4];
  float ss = v.x * v.x + v.y * v.y + v.z * v.z + v.w * v.w;
#pragma unroll
  for (int off = 1; off < 64; off <<= 1) ss += __shfl_xor(ss, off);
  const float r = 1.0f / fmaxf(sqrtf(ss), 1e-12f);
  ushort4 o;
  o.x = f2bf(v.x * r); o.y = f2bf(v.y * r);
  o.z = f2bf(v.z * r); o.w = f2bf(v.w * r);
  *(ushort4*)&B2[(size_t)k * CDIM + lane * 4] = o;
}

// ---------- coalesced z normalize + optional raw token-major copy ----------
__global__ __launch_bounds__(256) void k_norm_z(const float* __restrict__ z,
                                                unsigned short* __restrict__ A2,
                                                float* __restrict__ zT) {
  __shared__ float ssb[4][64];
  __shared__ float rn[64];
  __shared__ unsigned short tile[64 * 264];
  __shared__ float tileF[64 * 260];
  const int b = blockIdx.x >> 4, hw0 = (blockIdx.x & 15) * 64;
  const int tid = threadIdx.x, cg = tid >> 6, hwl = tid & 63;
  float ss = 0.f;
#pragma unroll 8
  for (int i = 0; i < 64; ++i) {
    const int c = cg + i * 4;
    const float x = z[((size_t)(b * CDIM + c) << 10) + hw0 + hwl];
    ss = fmaf(x, x, ss);
  }
  ssb[cg][hwl] = ss;
  __syncthreads();
  if (tid < 64) {
    const float t = ssb[0][tid] + ssb[1][tid] + ssb[2][tid] + ssb[3][tid];
    rn[tid] = 1.0f / fmaxf(sqrtf(t), 1e-12f);
  }
  __syncthreads();
  const float r = rn[hwl];
#pragma unroll 8
  for (int i = 0; i < 64; ++i) {
    const int c = cg + i * 4;
    const float x = z[((size_t)(b * CDIM + c) << 10) + hw0 + hwl];
    tile[hwl * 264 + c] = f2bf(x * r);
    tileF[hwl * 260 + c] = x;
  }
  __syncthreads();
  const int rr = tid >> 5, tt = tid & 31;
#pragma unroll
  for (int it = 0; it < 8; ++it) {
    const int row = rr + 8 * it;
    const int token = b * 1024 + hw0 + row;
    const uint4 v = *(const uint4*)&tile[row * 264 + tt * 8];
    *(uint4*)&A2[(size_t)token * CDIM + tt * 8] = v;
    if (zT != nullptr) {
      const float4 f0 = *(const float4*)&tileF[row * 260 + tt * 4];
      const float4 f1 = *(const float4*)&tileF[row * 260 + 128 + tt * 4];
      *(float4*)&zT[(size_t)token * CDIM + tt * 4] = f0;
      *(float4*)&zT[(size_t)token * CDIM + 128 + tt * 4] = f1;
    }
  }
}

// ============ pass 1: A in registers, B dbuf, 3 blocks/CU (no spill), t = 2*dot ============
__global__ __launch_bounds__(256, 3) void k_pass1(const unsigned short* __restrict__ A2,
    const unsigned short* __restrict__ B2,
    unsigned long long* __restrict__ cand, unsigned* __restrict__ cbc,
    unsigned* __restrict__ rowMaxU) {
  __shared__ alignas(16) unsigned short Bt[2][128 * 64];  // 2 x 16 KB B dbuf
  __shared__ unsigned smaxU[64];
  __shared__ unsigned lcnt;
  const int rt = blockIdx.x, chunk = blockIdx.y;   // swizzle: co-resident blocks share chunk
  const int r0 = rt * 64, k0 = chunk * CHSZ;
  const int blin = rt * NCH + chunk;
  const int tid = threadIdx.x, lane = tid & 63, w = tid >> 6;
  const int wrr = (w & 1) * 32, wc = (w >> 1) * 64;
  const int l15 = lane & 15, quad = lane >> 4;

  if (tid == 0) lcnt = 0u;
  if (tid < 64) smaxU[tid] = 0u;

  // A fragments -> registers (rows fixed per wave for whole kernel).
  short8 afr[2][4][2];
#pragma unroll
  for (int ti = 0; ti < 2; ++ti) {
    const size_t rbase = (size_t)(r0 + wrr + ti * 16 + l15) * CDIM;
#pragma unroll
    for (int st = 0; st < 4; ++st)
#pragma unroll
      for (int kk = 0; kk < 2; ++kk)
        afr[ti][st][kk] = *(const short8*)&A2[rbase + st * 64 + (((kk << 2) | quad) * 8)];
  }

  // per-thread B staging bases (swizzle: position cg holds global group cg^(row&7))
  const unsigned short* bsrc[4];
  unsigned bdst[4];
#pragma unroll
  for (int i = 0; i < 4; ++i) {
    const int lin = i * 256 + tid;
    const int row = lin >> 3, cg = lin & 7;
    const int gcg = cg ^ (row & 7);
    bsrc[i] = B2 + (size_t)(k0 + row) * CDIM + gcg * 8;
    bdst[i] = (unsigned)lin * 16u;
  }
#pragma unroll
  for (int i = 0; i < 4; ++i)
    async_load16(bsrc[i], (char*)Bt[0] + bdst[i]);

  // hoisted B LDS read offsets
  int boff[4][2];
#pragma unroll
  for (int tj = 0; tj < 4; ++tj) {
    const int br = wc + tj * 16 + l15;
#pragma unroll
    for (int kk = 0; kk < 2; ++kk)
      boff[tj][kk] = br * 64 + ((((kk << 2) | quad) ^ (br & 7)) * 8);
  }
  __syncthreads();

  f32x4 acc[2][4];

  for (int ct = 0; ct < 16; ++ct) {
#pragma unroll
    for (int ti = 0; ti < 2; ++ti)
#pragma unroll
      for (int tj = 0; tj < 4; ++tj) acc[ti][tj] = (f32x4){0.f, 0.f, 0.f, 0.f};

#pragma unroll
    for (int st = 0; st < 4; ++st) {
      if (!(ct == 15 && st == 3)) {
        const int noff = (st < 3) ? (st + 1) * 64 : 32768;
        char* dbuf = (char*)Bt[(st + 1) & 1];
#pragma unroll
        for (int i = 0; i < 4; ++i)
          async_load16(bsrc[i] + noff, dbuf + bdst[i]);
      }
      const unsigned short* bp = Bt[st & 1];
#pragma unroll
      for (int kk = 0; kk < 2; ++kk) {
        short8 bfr[4];
#pragma unroll
        for (int tj = 0; tj < 4; ++tj)
          bfr[tj] = *(const short8*)&bp[boff[tj][kk]];
#pragma unroll
        for (int ti = 0; ti < 2; ++ti)
#pragma unroll
          for (int tj = 0; tj < 4; ++tj)
            acc[ti][tj] = __builtin_amdgcn_mfma_f32_16x16x32_bf16(afr[ti][st][kk], bfr[tj],
                                                                  acc[ti][tj], 0, 0, 0);
      }
      if (st == 3) {
        const int kb = k0 + ct * 128;
#pragma unroll
        for (int ti = 0; ti < 2; ++ti)
#pragma unroll
          for (int tj = 0; tj < 4; ++tj) {
            f32x4 a = acc[ti][tj];
#pragma unroll
            for (int r = 0; r < 4; ++r) a[r] = a[r] + a[r];   // t = 2*dot
            acc[ti][tj] = a;
          }
#pragma unroll
        for (int ti = 0; ti < 2; ++ti)
#pragma unroll
          for (int r = 0; r < 4; ++r) {
            float mt = fmaxf(fmaxf(acc[ti][0][r], acc[ti][1][r]),
                             fmaxf(acc[ti][2][r], acc[ti][3][r]));
            mt = fmaxf(mt, __shfl_xor(mt, 1));
            mt = fmaxf(mt, __shfl_xor(mt, 2));
            mt = fmaxf(mt, __shfl_xor(mt, 4));
            mt = fmaxf(mt, __shfl_xor(mt, 8));
            if (l15 == 0) atomicMax(&smaxU[wrr + ti * 16 + quad * 4 + r], fkey(mt));
          }
        __syncthreads();   // all waves' maxes visible -> tight threshold
#pragma unroll
        for (int ti = 0; ti < 2; ++ti)
#pragma unroll
          for (int r = 0; r < 4; ++r) {
            const int rowloc = wrr + ti * 16 + quad * 4 + r;
            const float thr = keyf(smaxU[rowloc]) - DELTA_C;
            const unsigned rowg = (unsigned)(r0 + rowloc);
#pragma unroll
            for (int tj = 0; tj < 4; ++tj) {
              const float t = acc[ti][tj][r];
              if (t >= thr) {
                const unsigned slot = atomicAdd(&lcnt, 1u);
                if (slot < CAP_BLK) {
                  const unsigned pr = (rowg << 14) | (unsigned)(kb + wc + tj * 16 + l15);
                  cand[(size_t)blin * CAP_BLK + slot] =
                      ((unsigned long long)__float_as_uint(t) << 32) | pr;
                }
              }
            }
          }
      }
      __syncthreads();
    }
#pragma unroll
    for (int i = 0; i < 4; ++i) bsrc[i] += 32768;
  }
  if (tid < 64) atomicMax(&rowMaxU[r0 + tid], smaxU[tid]);
  if (tid == 0) cbc[blin] = lcnt < CAP_BLK ? lcnt : CAP_BLK;
}

// ---------- fused candidate processing: block = rt, LDS-local Z/E ----------
__global__ __launch_bounds__(256) void k_cstat2(const unsigned long long* __restrict__ cand,
    const unsigned* __restrict__ cbc, const unsigned* __restrict__ rowMaxU,
    float* __restrict__ colsum, unsigned* __restrict__ ntList,
    unsigned* __restrict__ ntc, float* __restrict__ scalars) {
  __shared__ float lM[64], lZ[64], lE[64], lIZ[64];
  __shared__ float sbuf[4];
  const int rt = blockIdx.x, r0 = rt * 64;
  const int tid = threadIdx.x, lane = tid & 63;
  if (tid < 64) {
    lM[tid] = keyf(rowMaxU[r0 + tid]);
    lZ[tid] = 0.f; lE[tid] = 0.f;
  }
  __syncthreads();
  for (int sub = 0; sub < NCH; ++sub) {
    const int blin = rt * NCH + sub;
    const unsigned cnt = cbc[blin] < CAP_BLK ? cbc[blin] : CAP_BLK;
    for (unsigned i = tid; i < cnt; i += 256u) {
      const unsigned long long e = cand[(size_t)blin * CAP_BLK + i];
      const unsigned pr = (unsigned)(e & 0xFFFFFFFu);
      const float t = __uint_as_float((unsigned)(e >> 32));
      const int rowl = (int)((pr >> 14) & 63u);
      const float d = t - lM[rowl];
      const float ex = exp2f(d * L2E100);
      atomicAdd(&lZ[rowl], ex);
      atomicAdd(&lE[rowl], d * 100.0f * ex);
    }
  }
  __syncthreads();
  float ent = 0.f;
  if (tid < 64) {
    const float Z = lZ[tid];
    lIZ[tid] = 1.0f / Z;
    ent = logf(Z) - lE[tid] / Z;
  }
  const float es = blockReduceSum256(ent, sbuf);
  if (tid == 0) atomicAdd(&scalars[1], es);
  __syncthreads();
  for (int sub = 0; sub < NCH; ++sub) {
    const int blin = rt * NCH + sub;
    const unsigned cnt = cbc[blin] < CAP_BLK ? cbc[blin] : CAP_BLK;
    const unsigned lim = (cnt + 255u) & ~255u;
    for (unsigned i = tid; i < lim; i += 256u) {
      bool nt = false;
      unsigned pr = 0u;
      if (i < cnt) {
        const unsigned long long e = cand[(size_t)blin * CAP_BLK + i];
        pr = (unsigned)(e & 0xFFFFFFFu);
        const float t = __uint_as_float((unsigned)(e >> 32));
        const int rowl = (int)((pr >> 14) & 63u);
        const float d = t - lM[rowl];
        atomicAdd(&colsum[pr & 0x3FFFu], exp2f(d * L2E100) * lIZ[rowl]);
        nt = (d >= -EPS_NT);
      }
      const unsigned long long mask = __ballot(nt);
      const unsigned cw = (unsigned)__popcll(mask);
      unsigned base = 0u;
      if (lane == 0 && cw) base = atomicAdd(ntc, cw);
      base = __shfl((int)base, 0);
      if (nt) {
        const unsigned off = (unsigned)__popcll(mask & ((1ull << lane) - 1ull));
        const unsigned s = base + off;
        if (s < NT_CAP) ntList[s] = pr;
      }
    }
  }
}

// ---------- fp64 re-rank of near-tie candidates (coalesced zT if available) ----------
__global__ __launch_bounds__(256) void k_refine(const float* __restrict__ z,
    const float* __restrict__ zT, const float* __restrict__ emb,
    const unsigned* __restrict__ ntList, const unsigned* __restrict__ ntc,
    unsigned long long* __restrict__ rowkey) {
  const unsigned cnt = *ntc;
  const unsigned lim = cnt < NT_CAP ? cnt : NT_CAP;
  const int lane = threadIdx.x & 63, wv = threadIdx.x >> 6;
  for (unsigned slot = blockIdx.x * 4 + wv; slot < lim; slot += gridDim.x * 4) {
    const unsigned pr = ntList[slot];
    const int n = (int)(pr >> 14), k = (int)(pr & 0x3FFFu);
    const int b = n >> 10, hw = n & 1023;
    double sz = 0.0, se = 0.0, sp = 0.0;
#pragma unroll
    for (int u = 0; u < CDIM / 64; ++u) {
      const int c = lane + u * 64;
      const double zv = (zT != nullptr)
          ? (double)zT[(size_t)n * CDIM + c]
          : (double)z[((size_t)(b * CDIM + c) << 10) + hw];
      const double ev = (double)emb[(size_t)k * CDIM + c];
      sz = fma(zv, zv, sz); se = fma(ev, ev, se); sp = fma(zv, ev, sp);
    }
    for (int off = 32; off; off >>= 1) {
      sz += __shfl_down(sz, off);
      se += __shfl_down(se, off);
      sp += __shfl_down(sp, off);
    }
    if (lane == 0) {
      const double nz = fmax(sqrt(sz), 1e-12);
      const double ne = fmax(sqrt(se), 1e-12);
      const double d = sz / (nz * nz) + se / (ne * ne) - 2.0 * sp / (nz * ne);
      const unsigned long long key =
          (((unsigned long long)(d * 140737488355328.0)) << 14) | (unsigned long long)k;
      atomicMin(&rowkey[n], key);
    }
  }
}

// ---------- z_q gather + idx extraction + vq sums ----------
__global__ __launch_bounds__(256) void k_zq(const unsigned short* __restrict__ A2,
    const unsigned short* __restrict__ B2, const unsigned long long* __restrict__ rowkey,
    const long long* __restrict__ qids, int* __restrict__ idxI,
    float* __restrict__ outIdxF, float* __restrict__ outZ,
    float* __restrict__ scalars) {
  __shared__ int lidx[64];
  __shared__ unsigned short tile[64 * 264];
  __shared__ float sbuf[4];
  const int b = blockIdx.x >> 4, hw0 = (blockIdx.x & 15) * 64;
  const int tid = threadIdx.x;
  if (tid < 64) {
    const int n = b * 1024 + hw0 + tid;
    const unsigned long long key = rowkey[n];
    const int k = (key != ~0ull) ? (int)(key & 0x3FFFull) : 0;
    lidx[tid] = k;
    idxI[n] = k;
    outIdxF[n] = (float)k;
  }
  __syncthreads();
  const long long qid = qids[b];
  const int rr = tid >> 5, tt = tid & 31;
  float vq = 0.f;
#pragma unroll
  for (int it = 0; it < 8; ++it) {
    const int row = rr + 8 * it;
    const int token = b * 1024 + hw0 + row;
    union { uint4 v; unsigned short s[8]; } ev, zv;
    ev.v = *(const uint4*)&B2[(size_t)lidx[row] * CDIM + tt * 8];
    zv.v = *(const uint4*)&A2[(size_t)token * CDIM + tt * 8];
    *(uint4*)&tile[row * 264 + tt * 8] = ev.v;
    float dd = 0.f;
#pragma unroll
    for (int u = 0; u < 8; ++u) {
      const float d = bf2f(ev.s[u]) - bf2f(zv.s[u]);
      dd = fmaf(d, d, dd);
    }
    if ((long long)(row & 31) <= qid) vq += dd;
  }
  const float s = blockReduceSum256(vq, sbuf);
  if (tid == 0) atomicAdd(&scalars[0], s * (1.0f / 256.0f));
  __syncthreads();
  const int cg = tid >> 6, hwl = tid & 63;
#pragma unroll 8
  for (int i = 0; i < 64; ++i) {
    const int c = cg + i * 4;
    outZ[((size_t)(b * CDIM + c) << 10) + hw0 + hwl] = bf2f(tile[hwl * 264 + c]);
  }
}

// ---------- final: avg-entropy from colsum + dead-code + scalar outputs ----------
__global__ __launch_bounds__(256) void k_final(const int* __restrict__ idxI,
    const long long* __restrict__ qids, const float* __restrict__ colsum,
    const float* __restrict__ scalars, float* __restrict__ out) {
  __shared__ float sbuf[4];
  const int tid = threadIdx.x;
  float ae = 0.f;
  for (int i = tid; i < N_E; i += 256) {
    const float q = colsum[i] * (1.0f / (float)N_TOK);
    ae += q * logf(q + 1e-5f);
  }
  const float aes = blockReduceSum256(ae, sbuf);   // = -avg_entropy
  int cnt = 0;
  for (int p = tid; p < 1024; p += 256) {
    const int v = idxI[p];
    bool eq = true;
    for (int b = 1; b < 16; ++b) eq = eq && (idxI[b * 1024 + p] == v);
    cnt += eq ? 1 : 0;
  }
  const float dc = blockReduceSum256((float)cnt, sbuf);
  if (tid == 0) {
    float denom = 0.f;
    for (int b = 0; b < 16; ++b) denom += (float)(qids[b] + 1ll);
    out[4194304] = scalars[0] / denom;
    out[4194305] = 0.25f * scalars[0] / denom;
    out[4194306] = 0.1f * (scalars[1] * (1.0f / (float)N_TOK) + aes);
    out[4194307] = dc * (1.0f / 1024.0f);
  }
}

extern "C" void kernel_launch(void* const* d_in, const int* in_sizes, int n_in,
                              void* d_out, int out_size, void* d_ws, size_t ws_size,
                              hipStream_t stream) {
  const float*      z    = (const float*)d_in[0];
  const float*      emb  = (const float*)d_in[1];
  const long long*  qids = (const long long*)d_in[2];
  float* out = (float*)d_out;
  float* W   = (float*)d_ws;

  unsigned short* A2 = (unsigned short*)(W + OFF_A2);
  unsigned short* B2 = (unsigned short*)(W + OFF_B2);
  unsigned* rowMaxU = (unsigned*)(W + OFF_RMX);
  float* colsum = W + OFF_CS;
  float* scal   = W + OFF_SC;
  unsigned long long* rowkey = (unsigned long long*)(W + OFF_RK);
  unsigned* ntList = (unsigned*)(W + OFF_NT);
  unsigned* ntc    = (unsigned*)(W + OFF_NTC);
  unsigned* cbc    = (unsigned*)(W + OFF_CBC);
  int* idxI        = (int*)(W + OFF_IDX);
  unsigned long long* cand = (unsigned long long*)(W + OFF_CAND);
  float* zT = (ws_size >= NEED_ZT_BYTES) ? (W + OFF_ZT) : (float*)nullptr;

  k_norm_emb<<<dim3(N_E / 4),     dim3(256), 0, stream>>>(emb, B2, colsum, scal,
                                                          rowkey, ntc, rowMaxU);
  k_norm_z  <<<dim3(256),         dim3(256), 0, stream>>>(z, A2, zT);
  k_pass1   <<<dim3(256, NCH),    dim3(256), 0, stream>>>(A2, B2, cand, cbc, rowMaxU);
  k_cstat2  <<<dim3(256),         dim3(256), 0, stream>>>(cand, cbc, rowMaxU, colsum,
                                                          ntList, ntc, scal);
  k_refine  <<<dim3(1024),        dim3(256), 0, stream>>>(z, zT, emb, ntList, ntc, rowkey);
  k_zq      <<<dim3(256),         dim3(256), 0, stream>>>(A2, B2, rowkey, qids,
                                                          idxI, out + 4194308, out, scal);
  k_final   <<<dim3(1),           dim3(256), 0, stream>>>(idxI, qids, colsum, scal, out);
}